// Round 1
// baseline (428.868 us; speedup 1.0000x reference)
//
#include <hip/hip_runtime.h>
#include <math.h>

#define NSH 1195
#define NU  805
#define NI  390
#define DD  64
#define BROWS 65536
#define ESH 100000
#define KC  78   // 390 = 5*78

// ---------------- ws layout (floats) ----------------
#define OFF_AGG   0u          // 76480
#define OFF_CNT   76480u      // 1280 (padded)
#define OFF_H1    77760u      // 76480
#define OFF_H2    154240u     // 76480
#define OFF_EH    230720u     // 51520
#define OFF_ES    282240u     // 24960
#define OFF_ESW   307200u     // 24960
#define OFF_STATS 332160u     // 128
#define OFF_BN    332288u     // 128
#define OFF_EPRE  332416u     // 4194304
// total = 4526720 floats = 18.1 MB

// ---------------- GCN aggregate: agg[dst] += x[src]; cnt[dst] += 1 ----------------
__global__ __launch_bounds__(256) void agg_kernel(const int* __restrict__ edges,
                                                  const float* __restrict__ x,
                                                  float* __restrict__ agg,
                                                  float* __restrict__ cnt,
                                                  int do_cnt) {
    int gid = blockIdx.x * 256 + threadIdx.x;
    int e = gid >> 6;
    int d = gid & 63;
    if (e < ESH) {
        int s = edges[e];
        int t = edges[ESH + e];
        atomicAdd(&agg[t * DD + d], x[s * DD + d]);
        if (do_cnt && d == 0) atomicAdd(&cnt[t], 1.0f);
    }
}

// ---------------- GCN transform: tanh((agg@W.T + cnt*b)/max(cnt,1)) ----------------
__global__ __launch_bounds__(256) void gcn_transform(const float* __restrict__ agg,
                                                     const float* __restrict__ cnt,
                                                     const float* __restrict__ W,
                                                     const float* __restrict__ b,
                                                     float* __restrict__ out) {
    __shared__ float s_wt[DD * DD];
    __shared__ float s_z[4 * DD];
    int tid = threadIdx.x;
    for (int i = tid; i < DD * DD; i += 256) {
        int j = i >> 6, k = i & 63;
        s_wt[k * DD + j] = W[i];
    }
    int w = tid >> 6, j = tid & 63;
    int node = blockIdx.x * 4 + w;
    bool active = node < NSH;
    s_z[w * DD + j] = active ? agg[node * DD + j] : 0.f;
    __syncthreads();
    float c = active ? cnt[node] : 0.f;
    float acc = c * b[j];
    #pragma unroll 8
    for (int k = 0; k < DD; k++)
        acc = fmaf(s_z[w * DD + k], s_wt[k * DD + j], acc);
    float h = tanhf(acc / fmaxf(c, 1.0f));
    if (active) out[node * DD + j] = h;
}

// ---------------- proj + l2norm: es/eh ----------------
__global__ __launch_bounds__(256) void proj_kernel(const float* __restrict__ h2,
                                                   const float* __restrict__ Wp1,
                                                   const float* __restrict__ bp1,
                                                   const float* __restrict__ Wp2,
                                                   const float* __restrict__ bp2,
                                                   float* __restrict__ eh,
                                                   float* __restrict__ es) {
    __shared__ float s_w1[DD * DD], s_w2[DD * DD];
    __shared__ float s_z[4 * DD], s_t[4 * DD];
    int tid = threadIdx.x;
    for (int i = tid; i < DD * DD; i += 256) {
        int j = i >> 6, k = i & 63;
        s_w1[k * DD + j] = Wp1[i];
        s_w2[k * DD + j] = Wp2[i];
    }
    int w = tid >> 6, j = tid & 63;
    int node = blockIdx.x * 4 + w;
    bool active = node < NSH;
    s_z[w * DD + j] = active ? h2[node * DD + j] : 0.f;
    __syncthreads();
    float acc = bp1[j];
    #pragma unroll 8
    for (int k = 0; k < DD; k++)
        acc = fmaf(s_z[w * DD + k], s_w1[k * DD + j], acc);
    float t = acc > 0.f ? acc : expm1f(acc);
    s_t[w * DD + j] = t;
    __syncthreads();
    float o = bp2[j];
    #pragma unroll 8
    for (int k = 0; k < DD; k++)
        o = fmaf(s_t[w * DD + k], s_w2[k * DD + j], o);
    float sq = o * o;
    #pragma unroll
    for (int off = 1; off < 64; off <<= 1) sq += __shfl_xor(sq, off);
    float r = o / sqrtf(sq);
    if (active) {
        if (node < NU) eh[node * DD + j] = r;
        else           es[(node - NU) * DD + j] = r;
    }
}

// ---------------- esW = es @ Wm.T ----------------
__global__ __launch_bounds__(256) void projm_kernel(const float* __restrict__ es,
                                                    const float* __restrict__ Wm,
                                                    float* __restrict__ esW) {
    __shared__ float s_wt[DD * DD];
    __shared__ float s_z[4 * DD];
    int tid = threadIdx.x;
    for (int i = tid; i < DD * DD; i += 256) {
        int j = i >> 6, k = i & 63;
        s_wt[k * DD + j] = Wm[i];
    }
    int w = tid >> 6, j = tid & 63;
    int r = blockIdx.x * 4 + w;
    bool active = r < NI;
    s_z[w * DD + j] = active ? es[r * DD + j] : 0.f;
    __syncthreads();
    float o = 0.f;
    #pragma unroll 8
    for (int k = 0; k < DD; k++)
        o = fmaf(s_z[w * DD + k], s_wt[k * DD + j], o);
    if (active) esW[r * DD + j] = o;
}

// ---------------- e_pre = (P @ esW)/rowsum(P) + bm ; accumulate BN stats ----------------
__global__ __launch_bounds__(256) void synd_kernel(const float* __restrict__ P,
                                                   const float* __restrict__ esW,
                                                   const float* __restrict__ bm,
                                                   float* __restrict__ e_pre,
                                                   float* __restrict__ stats) {
    __shared__ float s_es[KC * DD];   // 4992 floats
    __shared__ float s_P[64 * KC];    // 4992 floats
    int tid = threadIdx.x;
    int w = tid >> 6, c = tid & 63;
    int r0 = blockIdx.x * 64;
    float acc[16], rs[16];
    #pragma unroll
    for (int i = 0; i < 16; i++) { acc[i] = 0.f; rs[i] = 0.f; }

    for (int ck = 0; ck < 5; ck++) {
        int k0 = ck * KC;
        __syncthreads();
        for (int i = tid; i < KC * DD; i += 256) s_es[i] = esW[k0 * DD + i];
        for (int i = tid; i < 64 * KC; i += 256) {
            int r = i / KC, k = i - r * KC;
            s_P[i] = P[(size_t)(r0 + r) * NI + k0 + k];
        }
        __syncthreads();
        // lane-partial row sums (k = c and c+64 within this chunk)
        #pragma unroll
        for (int rr = 0; rr < 16; rr++) {
            const float* prow = &s_P[(w * 16 + rr) * KC];
            float v = prow[c];
            if (c < KC - 64) v += prow[c + 64];
            rs[rr] += v;
        }
        for (int kk = 0; kk < KC; kk += 2) {
            float e0 = s_es[kk * DD + c];
            float e1 = s_es[(kk + 1) * DD + c];
            #pragma unroll
            for (int rr = 0; rr < 16; rr++) {
                float2 p = *(const float2*)&s_P[(w * 16 + rr) * KC + kk];
                acc[rr] = fmaf(p.x, e0, acc[rr]);
                acc[rr] = fmaf(p.y, e1, acc[rr]);
            }
        }
    }
    // full row sums (all lanes get the value)
    #pragma unroll
    for (int rr = 0; rr < 16; rr++) {
        float v = rs[rr];
        #pragma unroll
        for (int off = 1; off < 64; off <<= 1) v += __shfl_xor(v, off);
        rs[rr] = v;
    }
    float bmc = bm[c];
    float ssum = 0.f, ssq = 0.f;
    #pragma unroll
    for (int rr = 0; rr < 16; rr++) {
        float v = acc[rr] / rs[rr] + bmc;
        e_pre[(size_t)(r0 + w * 16 + rr) * DD + c] = v;
        ssum += v;
        ssq = fmaf(v, v, ssq);
    }
    __syncthreads();
    s_P[tid] = ssum;
    s_P[256 + tid] = ssq;
    __syncthreads();
    if (tid < 64) {
        float a = s_P[tid] + s_P[tid + 64] + s_P[tid + 128] + s_P[tid + 192];
        float q = s_P[256 + tid] + s_P[256 + tid + 64] + s_P[256 + tid + 128] + s_P[256 + tid + 192];
        atomicAdd(&stats[tid], a);
        atomicAdd(&stats[64 + tid], q);
    }
}

// ---------------- BN params ----------------
__global__ void bn_finalize(const float* __restrict__ stats,
                            const float* __restrict__ gamma,
                            const float* __restrict__ beta,
                            float* __restrict__ bn) {
    int t = threadIdx.x;
    if (t < 64) {
        float mu  = stats[t] * (1.0f / 65536.0f);
        float ex2 = stats[64 + t] * (1.0f / 65536.0f);
        float var = ex2 - mu * mu;
        float rstd = 1.0f / sqrtf(var + 1e-5f);
        float sc = rstd * gamma[t];
        bn[t] = sc;
        bn[64 + t] = beta[t] - mu * sc;
    }
}

// ---------------- out = relu(BN(e_pre)) @ eh.T ----------------
#define CT 128
__global__ __launch_bounds__(256) void out_kernel(const float* __restrict__ e_pre,
                                                  const float* __restrict__ eh,
                                                  const float* __restrict__ bn,
                                                  float* __restrict__ out) {
    __shared__ float s_e[64 * DD];      // 4096 floats
    __shared__ float s_ehT[DD * 132];   // padded: b128-aligned, conflict-free
    int tid = threadIdx.x;
    int r0 = blockIdx.y * 64;
    int c0 = blockIdx.x * CT;
    int cw = min(CT, NU - c0);
    for (int i = tid; i < 64 * DD; i += 256) {
        int j = i & 63;
        float v = e_pre[(size_t)r0 * DD + i];
        s_e[i] = fmaxf(fmaf(v, bn[j], bn[64 + j]), 0.f);
    }
    for (int i = tid; i < CT * DD; i += 256) {
        int cc = i >> 6, k = i & 63;
        float v = (cc < cw) ? eh[(size_t)(c0 + cc) * DD + k] : 0.f;
        s_ehT[k * 132 + cc] = v;
    }
    __syncthreads();
    int tc = tid & 31, tr = tid >> 5;
    float acc[8][4];
    #pragma unroll
    for (int i = 0; i < 8; i++)
        #pragma unroll
        for (int j = 0; j < 4; j++) acc[i][j] = 0.f;
    for (int k = 0; k < DD; k++) {
        float4 bq = *(const float4*)&s_ehT[k * 132 + tc * 4];
        #pragma unroll
        for (int i = 0; i < 8; i++) {
            float a = s_e[(tr * 8 + i) * DD + k];
            acc[i][0] = fmaf(a, bq.x, acc[i][0]);
            acc[i][1] = fmaf(a, bq.y, acc[i][1]);
            acc[i][2] = fmaf(a, bq.z, acc[i][2]);
            acc[i][3] = fmaf(a, bq.w, acc[i][3]);
        }
    }
    #pragma unroll
    for (int i = 0; i < 8; i++) {
        int row = r0 + tr * 8 + i;
        #pragma unroll
        for (int j = 0; j < 4; j++) {
            int col = tc * 4 + j;
            if (col < cw) out[(size_t)row * NU + c0 + col] = acc[i][j];
        }
    }
}

// ---------------- launcher ----------------
extern "C" void kernel_launch(void* const* d_in, const int* in_sizes, int n_in,
                              void* d_out, int out_size, void* d_ws, size_t ws_size,
                              hipStream_t stream) {
    const int*   eSH   = (const int*)d_in[0];
    const float* presc = (const float*)d_in[3];
    const float* shemb = (const float*)d_in[4];
    const float* W1  = (const float*)d_in[5];
    const float* b1  = (const float*)d_in[6];
    const float* W2  = (const float*)d_in[7];
    const float* b2  = (const float*)d_in[8];
    const float* Wp1 = (const float*)d_in[9];
    const float* bp1 = (const float*)d_in[10];
    const float* Wp2 = (const float*)d_in[11];
    const float* bp2 = (const float*)d_in[12];
    const float* Wm  = (const float*)d_in[13];
    const float* bm  = (const float*)d_in[14];
    const float* gam = (const float*)d_in[15];
    const float* bet = (const float*)d_in[16];

    float* ws    = (float*)d_ws;
    float* agg   = ws + OFF_AGG;
    float* cnt   = ws + OFF_CNT;
    float* h1    = ws + OFF_H1;
    float* h2    = ws + OFF_H2;
    float* eh    = ws + OFF_EH;
    float* es    = ws + OFF_ES;
    float* esW   = ws + OFF_ESW;
    float* stats = ws + OFF_STATS;
    float* bnp   = ws + OFF_BN;
    float* e_pre = ws + OFF_EPRE;
    float* out   = (float*)d_out;

    // zero accumulators (agg+cnt contiguous), stats
    hipMemsetAsync(agg, 0, (76480 + 1280) * sizeof(float), stream);
    hipMemsetAsync(stats, 0, 128 * sizeof(float), stream);

    agg_kernel<<<25000, 256, 0, stream>>>(eSH, shemb, agg, cnt, 1);
    gcn_transform<<<299, 256, 0, stream>>>(agg, cnt, W1, b1, h1);
    hipMemsetAsync(agg, 0, 76480 * sizeof(float), stream);
    agg_kernel<<<25000, 256, 0, stream>>>(eSH, h1, agg, cnt, 0);
    gcn_transform<<<299, 256, 0, stream>>>(agg, cnt, W2, b2, h2);
    proj_kernel<<<299, 256, 0, stream>>>(h2, Wp1, bp1, Wp2, bp2, eh, es);
    projm_kernel<<<98, 256, 0, stream>>>(es, Wm, esW);
    synd_kernel<<<1024, 256, 0, stream>>>(presc, esW, bm, e_pre, stats);
    bn_finalize<<<1, 64, 0, stream>>>(stats, gam, bet, bnp);
    out_kernel<<<dim3(7, 1024), 256, 0, stream>>>(e_pre, eh, bnp, out);
}

// Round 2
// 354.890 us; speedup vs baseline: 1.2085x; 1.2085x over previous
//
#include <hip/hip_runtime.h>
#include <math.h>

#define NSH 1195
#define NU  805
#define NI  390
#define DD  64
#define BROWS 65536
#define ESH 100000
#define KC  78   // 390 = 5*78
#define NUPAD 832  // 13*64, eh16 padded rows

typedef _Float16 f16;
typedef _Float16 f16x8 __attribute__((ext_vector_type(8)));
typedef float f32x4 __attribute__((ext_vector_type(4)));

// ---------------- ws layout (floats) ----------------
#define OFF_AGG   0u          // 76480
#define OFF_CNT   76480u      // 1280 (padded)
#define OFF_H1    77760u      // 76480
#define OFF_H2    154240u     // 76480
#define OFF_EH    230720u     // eh16: 832*64 f16 = 26624 floats-worth; region has 51520
#define OFF_ES    282240u     // 24960
#define OFF_ESW   307200u     // 24960
#define OFF_STATS 332160u     // 128
#define OFF_BN    332288u     // 128
#define OFF_EPRE  332416u     // 4194304
// total = 4526720 floats = 18.1 MB

// ---------------- GCN aggregate: agg[dst] += x[src]; cnt[dst] += 1 ----------------
__global__ __launch_bounds__(256) void agg_kernel(const int* __restrict__ edges,
                                                  const float* __restrict__ x,
                                                  float* __restrict__ agg,
                                                  float* __restrict__ cnt,
                                                  int do_cnt) {
    int gid = blockIdx.x * 256 + threadIdx.x;
    int e = gid >> 6;
    int d = gid & 63;
    if (e < ESH) {
        int s = edges[e];
        int t = edges[ESH + e];
        atomicAdd(&agg[t * DD + d], x[s * DD + d]);
        if (do_cnt && d == 0) atomicAdd(&cnt[t], 1.0f);
    }
}

// ---------------- GCN transform: tanh((agg@W.T + cnt*b)/max(cnt,1)) ----------------
__global__ __launch_bounds__(256) void gcn_transform(const float* __restrict__ agg,
                                                     const float* __restrict__ cnt,
                                                     const float* __restrict__ W,
                                                     const float* __restrict__ b,
                                                     float* __restrict__ out) {
    __shared__ float s_wt[DD * DD];
    __shared__ float s_z[4 * DD];
    int tid = threadIdx.x;
    for (int i = tid; i < DD * DD; i += 256) {
        int j = i >> 6, k = i & 63;
        s_wt[k * DD + j] = W[i];
    }
    int w = tid >> 6, j = tid & 63;
    int node = blockIdx.x * 4 + w;
    bool active = node < NSH;
    s_z[w * DD + j] = active ? agg[node * DD + j] : 0.f;
    __syncthreads();
    float c = active ? cnt[node] : 0.f;
    float acc = c * b[j];
    #pragma unroll 8
    for (int k = 0; k < DD; k++)
        acc = fmaf(s_z[w * DD + k], s_wt[k * DD + j], acc);
    float h = tanhf(acc / fmaxf(c, 1.0f));
    if (active) out[node * DD + j] = h;
}

// ---------------- proj + l2norm: es (f32) / eh (f16) ----------------
__global__ __launch_bounds__(256) void proj_kernel(const float* __restrict__ h2,
                                                   const float* __restrict__ Wp1,
                                                   const float* __restrict__ bp1,
                                                   const float* __restrict__ Wp2,
                                                   const float* __restrict__ bp2,
                                                   f16* __restrict__ eh16,
                                                   float* __restrict__ es) {
    __shared__ float s_w1[DD * DD], s_w2[DD * DD];
    __shared__ float s_z[4 * DD], s_t[4 * DD];
    int tid = threadIdx.x;
    for (int i = tid; i < DD * DD; i += 256) {
        int j = i >> 6, k = i & 63;
        s_w1[k * DD + j] = Wp1[i];
        s_w2[k * DD + j] = Wp2[i];
    }
    int w = tid >> 6, j = tid & 63;
    int node = blockIdx.x * 4 + w;
    bool active = node < NSH;
    s_z[w * DD + j] = active ? h2[node * DD + j] : 0.f;
    __syncthreads();
    float acc = bp1[j];
    #pragma unroll 8
    for (int k = 0; k < DD; k++)
        acc = fmaf(s_z[w * DD + k], s_w1[k * DD + j], acc);
    float t = acc > 0.f ? acc : expm1f(acc);
    s_t[w * DD + j] = t;
    __syncthreads();
    float o = bp2[j];
    #pragma unroll 8
    for (int k = 0; k < DD; k++)
        o = fmaf(s_t[w * DD + k], s_w2[k * DD + j], o);
    float sq = o * o;
    #pragma unroll
    for (int off = 1; off < 64; off <<= 1) sq += __shfl_xor(sq, off);
    float r = o / sqrtf(sq);
    if (active) {
        if (node < NU) eh16[node * DD + j] = (f16)r;
        else           es[(node - NU) * DD + j] = r;
    }
}

// ---------------- esW = es @ Wm.T ----------------
__global__ __launch_bounds__(256) void projm_kernel(const float* __restrict__ es,
                                                    const float* __restrict__ Wm,
                                                    float* __restrict__ esW) {
    __shared__ float s_wt[DD * DD];
    __shared__ float s_z[4 * DD];
    int tid = threadIdx.x;
    for (int i = tid; i < DD * DD; i += 256) {
        int j = i >> 6, k = i & 63;
        s_wt[k * DD + j] = Wm[i];
    }
    int w = tid >> 6, j = tid & 63;
    int r = blockIdx.x * 4 + w;
    bool active = r < NI;
    s_z[w * DD + j] = active ? es[r * DD + j] : 0.f;
    __syncthreads();
    float o = 0.f;
    #pragma unroll 8
    for (int k = 0; k < DD; k++)
        o = fmaf(s_z[w * DD + k], s_wt[k * DD + j], o);
    if (active) esW[r * DD + j] = o;
}

// ---------------- e_pre = (P @ esW)/rowsum(P) + bm ; accumulate BN stats ----------------
__global__ __launch_bounds__(256) void synd_kernel(const float* __restrict__ P,
                                                   const float* __restrict__ esW,
                                                   const float* __restrict__ bm,
                                                   float* __restrict__ e_pre,
                                                   float* __restrict__ stats) {
    __shared__ float s_es[KC * DD];   // 4992 floats
    __shared__ float s_P[64 * KC];    // 4992 floats
    int tid = threadIdx.x;
    int w = tid >> 6, c = tid & 63;
    int r0 = blockIdx.x * 64;
    float acc[16], rs[16];
    #pragma unroll
    for (int i = 0; i < 16; i++) { acc[i] = 0.f; rs[i] = 0.f; }

    for (int ck = 0; ck < 5; ck++) {
        int k0 = ck * KC;
        __syncthreads();
        for (int i = tid; i < KC * DD; i += 256) s_es[i] = esW[k0 * DD + i];
        for (int i = tid; i < 64 * KC; i += 256) {
            int r = i / KC, k = i - r * KC;
            s_P[i] = P[(size_t)(r0 + r) * NI + k0 + k];
        }
        __syncthreads();
        #pragma unroll
        for (int rr = 0; rr < 16; rr++) {
            const float* prow = &s_P[(w * 16 + rr) * KC];
            float v = prow[c];
            if (c < KC - 64) v += prow[c + 64];
            rs[rr] += v;
        }
        for (int kk = 0; kk < KC; kk += 2) {
            float e0 = s_es[kk * DD + c];
            float e1 = s_es[(kk + 1) * DD + c];
            #pragma unroll
            for (int rr = 0; rr < 16; rr++) {
                float2 p = *(const float2*)&s_P[(w * 16 + rr) * KC + kk];
                acc[rr] = fmaf(p.x, e0, acc[rr]);
                acc[rr] = fmaf(p.y, e1, acc[rr]);
            }
        }
    }
    #pragma unroll
    for (int rr = 0; rr < 16; rr++) {
        float v = rs[rr];
        #pragma unroll
        for (int off = 1; off < 64; off <<= 1) v += __shfl_xor(v, off);
        rs[rr] = v;
    }
    float bmc = bm[c];
    float ssum = 0.f, ssq = 0.f;
    #pragma unroll
    for (int rr = 0; rr < 16; rr++) {
        float v = acc[rr] / rs[rr] + bmc;
        e_pre[(size_t)(r0 + w * 16 + rr) * DD + c] = v;
        ssum += v;
        ssq = fmaf(v, v, ssq);
    }
    __syncthreads();
    s_P[tid] = ssum;
    s_P[256 + tid] = ssq;
    __syncthreads();
    if (tid < 64) {
        float a = s_P[tid] + s_P[tid + 64] + s_P[tid + 128] + s_P[tid + 192];
        float q = s_P[256 + tid] + s_P[256 + tid + 64] + s_P[256 + tid + 128] + s_P[256 + tid + 192];
        atomicAdd(&stats[tid], a);
        atomicAdd(&stats[64 + tid], q);
    }
}

// ---------------- BN params ----------------
__global__ void bn_finalize(const float* __restrict__ stats,
                            const float* __restrict__ gamma,
                            const float* __restrict__ beta,
                            float* __restrict__ bn) {
    int t = threadIdx.x;
    if (t < 64) {
        float mu  = stats[t] * (1.0f / 65536.0f);
        float ex2 = stats[64 + t] * (1.0f / 65536.0f);
        float var = ex2 - mu * mu;
        float rstd = 1.0f / sqrtf(var + 1e-5f);
        float sc = rstd * gamma[t];
        bn[t] = sc;
        bn[64 + t] = beta[t] - mu * sc;
    }
}

// ---------------- out = relu(BN(e_pre)) @ eh.T  via f16 MFMA ----------------
// A frag (16x32): lane l holds A[l&15][8*(l>>4)+i], i=0..7  (16B contiguous)
// B frag (32x16): lane l holds B[8*(l>>4)+i][l&15] = eh[col0+(l&15)][8*(l>>4)+i]
// C/D: col=lane&15, row=(lane>>4)*4+reg  (m89-verified layout)
__global__ __launch_bounds__(256) void out_mfma(const float* __restrict__ e_pre,
                                                const f16* __restrict__ eh16,
                                                const float* __restrict__ bn,
                                                float* __restrict__ out) {
    int tid = threadIdx.x;
    int lane = tid & 63, wid = tid >> 6;
    int wr = wid >> 1, wc = wid & 1;
    int l15 = lane & 15, lk = lane >> 4;
    int r0 = blockIdx.y * 64 + wr * 32;
    int c0 = blockIdx.x * 64 + wc * 32;

    // BN scale/offset for this lane's k-columns at each k-step
    float sc[2][8], of[2][8];
    #pragma unroll
    for (int ks = 0; ks < 2; ks++) {
        int kb = ks * 32 + lk * 8;
        f32x4 s0 = *(const f32x4*)&bn[kb];
        f32x4 s1 = *(const f32x4*)&bn[kb + 4];
        f32x4 o0 = *(const f32x4*)&bn[64 + kb];
        f32x4 o1 = *(const f32x4*)&bn[64 + kb + 4];
        #pragma unroll
        for (int i = 0; i < 4; i++) {
            sc[ks][i] = s0[i]; sc[ks][4 + i] = s1[i];
            of[ks][i] = o0[i]; of[ks][4 + i] = o1[i];
        }
    }

    // A fragments: fused BN + relu + f16 convert
    f16x8 afr[2][2];   // [mi][ks]
    #pragma unroll
    for (int mi = 0; mi < 2; mi++) {
        const float* pr = e_pre + (size_t)(r0 + mi * 16 + l15) * DD;
        #pragma unroll
        for (int ks = 0; ks < 2; ks++) {
            int kb = ks * 32 + lk * 8;
            f32x4 v0 = *(const f32x4*)&pr[kb];
            f32x4 v1 = *(const f32x4*)&pr[kb + 4];
            f16x8 a;
            #pragma unroll
            for (int i = 0; i < 4; i++) {
                a[i]     = (f16)fmaxf(fmaf(v0[i], sc[ks][i],     of[ks][i]),     0.f);
                a[4 + i] = (f16)fmaxf(fmaf(v1[i], sc[ks][4 + i], of[ks][4 + i]), 0.f);
            }
            afr[mi][ks] = a;
        }
    }

    // B fragments: direct f16 loads from eh16 (L2/L3 resident)
    f16x8 bfr[2][2];   // [ni][ks]
    #pragma unroll
    for (int ni = 0; ni < 2; ni++) {
        const f16* pc = eh16 + (size_t)(c0 + ni * 16 + l15) * DD;
        #pragma unroll
        for (int ks = 0; ks < 2; ks++)
            bfr[ni][ks] = *(const f16x8*)&pc[ks * 32 + lk * 8];
    }

    f32x4 acc[2][2];
    #pragma unroll
    for (int mi = 0; mi < 2; mi++)
        #pragma unroll
        for (int ni = 0; ni < 2; ni++)
            acc[mi][ni] = (f32x4){0.f, 0.f, 0.f, 0.f};

    #pragma unroll
    for (int ks = 0; ks < 2; ks++)
        #pragma unroll
        for (int mi = 0; mi < 2; mi++)
            #pragma unroll
            for (int ni = 0; ni < 2; ni++)
                acc[mi][ni] = __builtin_amdgcn_mfma_f32_16x16x32_f16(
                    afr[mi][ks], bfr[ni][ks], acc[mi][ni], 0, 0, 0);

    #pragma unroll
    for (int mi = 0; mi < 2; mi++) {
        #pragma unroll
        for (int ni = 0; ni < 2; ni++) {
            int col = c0 + ni * 16 + l15;
            if (col < NU) {
                #pragma unroll
                for (int j = 0; j < 4; j++) {
                    int row = r0 + mi * 16 + lk * 4 + j;
                    out[(size_t)row * NU + col] = acc[mi][ni][j];
                }
            }
        }
    }
}

// ---------------- launcher ----------------
extern "C" void kernel_launch(void* const* d_in, const int* in_sizes, int n_in,
                              void* d_out, int out_size, void* d_ws, size_t ws_size,
                              hipStream_t stream) {
    const int*   eSH   = (const int*)d_in[0];
    const float* presc = (const float*)d_in[3];
    const float* shemb = (const float*)d_in[4];
    const float* W1  = (const float*)d_in[5];
    const float* b1  = (const float*)d_in[6];
    const float* W2  = (const float*)d_in[7];
    const float* b2  = (const float*)d_in[8];
    const float* Wp1 = (const float*)d_in[9];
    const float* bp1 = (const float*)d_in[10];
    const float* Wp2 = (const float*)d_in[11];
    const float* bp2 = (const float*)d_in[12];
    const float* Wm  = (const float*)d_in[13];
    const float* bm  = (const float*)d_in[14];
    const float* gam = (const float*)d_in[15];
    const float* bet = (const float*)d_in[16];

    float* ws    = (float*)d_ws;
    float* agg   = ws + OFF_AGG;
    float* cnt   = ws + OFF_CNT;
    float* h1    = ws + OFF_H1;
    float* h2    = ws + OFF_H2;
    f16*   eh16  = (f16*)(ws + OFF_EH);
    float* es    = ws + OFF_ES;
    float* esW   = ws + OFF_ESW;
    float* stats = ws + OFF_STATS;
    float* bnp   = ws + OFF_BN;
    float* e_pre = ws + OFF_EPRE;
    float* out   = (float*)d_out;

    hipMemsetAsync(agg, 0, (76480 + 1280) * sizeof(float), stream);
    hipMemsetAsync(stats, 0, 128 * sizeof(float), stream);
    hipMemsetAsync(eh16, 0, (size_t)NUPAD * DD * sizeof(f16), stream);

    agg_kernel<<<25000, 256, 0, stream>>>(eSH, shemb, agg, cnt, 1);
    gcn_transform<<<299, 256, 0, stream>>>(agg, cnt, W1, b1, h1);
    hipMemsetAsync(agg, 0, 76480 * sizeof(float), stream);
    agg_kernel<<<25000, 256, 0, stream>>>(eSH, h1, agg, cnt, 0);
    gcn_transform<<<299, 256, 0, stream>>>(agg, cnt, W2, b2, h2);
    proj_kernel<<<299, 256, 0, stream>>>(h2, Wp1, bp1, Wp2, bp2, eh16, es);
    projm_kernel<<<98, 256, 0, stream>>>(es, Wm, esW);
    synd_kernel<<<1024, 256, 0, stream>>>(presc, esW, bm, e_pre, stats);
    bn_finalize<<<1, 64, 0, stream>>>(stats, gam, bet, bnp);
    out_mfma<<<dim3(13, 1024), 256, 0, stream>>>(e_pre, eh16, bnp, out);
}

// Round 3
// 274.389 us; speedup vs baseline: 1.5630x; 1.2934x over previous
//
#include <hip/hip_runtime.h>
#include <math.h>

#define NSH 1195
#define NU  805
#define NI  390
#define DD  64
#define BROWS 65536
#define ESH 100000
#define KPAD 416   // 13*32
#define NUPAD 832  // 13*64, eh16 padded rows

typedef _Float16 f16;
typedef _Float16 f16x8 __attribute__((ext_vector_type(8)));
typedef float f32x4 __attribute__((ext_vector_type(4)));

// ---------------- ws layout (floats) ----------------
#define OFF_AGG   0u          // 76480
#define OFF_CNT   76480u      // 1280 (padded)
#define OFF_H1    77760u      // 76480
#define OFF_H2    154240u     // 76480
#define OFF_EH    230720u     // eh16: 832*64 f16
#define OFF_ES    282240u     // 24960
#define OFF_ESWT  307200u     // esWT16: 64*416 f16 = 13312 floats-worth
#define OFF_STATS 332160u     // 128
#define OFF_BN    332288u     // 128
#define OFF_EPRE  332416u     // 4194304

// ---------------- GCN aggregate ----------------
__global__ __launch_bounds__(256) void agg_kernel(const int* __restrict__ edges,
                                                  const float* __restrict__ x,
                                                  float* __restrict__ agg,
                                                  float* __restrict__ cnt,
                                                  int do_cnt) {
    int gid = blockIdx.x * 256 + threadIdx.x;
    int e = gid >> 6;
    int d = gid & 63;
    if (e < ESH) {
        int s = edges[e];
        int t = edges[ESH + e];
        atomicAdd(&agg[t * DD + d], x[s * DD + d]);
        if (do_cnt && d == 0) atomicAdd(&cnt[t], 1.0f);
    }
}

// ---------------- GCN transform ----------------
__global__ __launch_bounds__(256) void gcn_transform(const float* __restrict__ agg,
                                                     const float* __restrict__ cnt,
                                                     const float* __restrict__ W,
                                                     const float* __restrict__ b,
                                                     float* __restrict__ out) {
    __shared__ float s_wt[DD * DD];
    __shared__ float s_z[4 * DD];
    int tid = threadIdx.x;
    for (int i = tid; i < DD * DD; i += 256) {
        int j = i >> 6, k = i & 63;
        s_wt[k * DD + j] = W[i];
    }
    int w = tid >> 6, j = tid & 63;
    int node = blockIdx.x * 4 + w;
    bool active = node < NSH;
    s_z[w * DD + j] = active ? agg[node * DD + j] : 0.f;
    __syncthreads();
    float c = active ? cnt[node] : 0.f;
    float acc = c * b[j];
    #pragma unroll 8
    for (int k = 0; k < DD; k++)
        acc = fmaf(s_z[w * DD + k], s_wt[k * DD + j], acc);
    float h = tanhf(acc / fmaxf(c, 1.0f));
    if (active) out[node * DD + j] = h;
}

// ---------------- proj + l2norm: es (f32) / eh (f16) ----------------
__global__ __launch_bounds__(256) void proj_kernel(const float* __restrict__ h2,
                                                   const float* __restrict__ Wp1,
                                                   const float* __restrict__ bp1,
                                                   const float* __restrict__ Wp2,
                                                   const float* __restrict__ bp2,
                                                   f16* __restrict__ eh16,
                                                   float* __restrict__ es) {
    __shared__ float s_w1[DD * DD], s_w2[DD * DD];
    __shared__ float s_z[4 * DD], s_t[4 * DD];
    int tid = threadIdx.x;
    for (int i = tid; i < DD * DD; i += 256) {
        int j = i >> 6, k = i & 63;
        s_w1[k * DD + j] = Wp1[i];
        s_w2[k * DD + j] = Wp2[i];
    }
    int w = tid >> 6, j = tid & 63;
    int node = blockIdx.x * 4 + w;
    bool active = node < NSH;
    s_z[w * DD + j] = active ? h2[node * DD + j] : 0.f;
    __syncthreads();
    float acc = bp1[j];
    #pragma unroll 8
    for (int k = 0; k < DD; k++)
        acc = fmaf(s_z[w * DD + k], s_w1[k * DD + j], acc);
    float t = acc > 0.f ? acc : expm1f(acc);
    s_t[w * DD + j] = t;
    __syncthreads();
    float o = bp2[j];
    #pragma unroll 8
    for (int k = 0; k < DD; k++)
        o = fmaf(s_t[w * DD + k], s_w2[k * DD + j], o);
    float sq = o * o;
    #pragma unroll
    for (int off = 1; off < 64; off <<= 1) sq += __shfl_xor(sq, off);
    float r = o / sqrtf(sq);
    if (active) {
        if (node < NU) eh16[node * DD + j] = (f16)r;
        else           es[(node - NU) * DD + j] = r;
    }
}

// ---------------- esWT16[n][k] = (es @ Wm.T)[k][n] as f16, K padded ----------------
__global__ __launch_bounds__(256) void projm_kernel(const float* __restrict__ es,
                                                    const float* __restrict__ Wm,
                                                    f16* __restrict__ esWT) {
    __shared__ float s_wt[DD * DD];
    __shared__ float s_z[4 * DD];
    int tid = threadIdx.x;
    for (int i = tid; i < DD * DD; i += 256) {
        int j = i >> 6, k = i & 63;
        s_wt[k * DD + j] = Wm[i];
    }
    int w = tid >> 6, j = tid & 63;
    int r = blockIdx.x * 4 + w;
    bool active = r < NI;
    s_z[w * DD + j] = active ? es[r * DD + j] : 0.f;
    __syncthreads();
    float o = 0.f;
    #pragma unroll 8
    for (int k = 0; k < DD; k++)
        o = fmaf(s_z[w * DD + k], s_wt[k * DD + j], o);
    if (active) esWT[j * KPAD + r] = (f16)o;
}

// ---------------- e_pre = (P @ esW)/rowsum(P) + bm via f16 MFMA; BN stats ----------------
__global__ __launch_bounds__(256) void synd_mfma(const float* __restrict__ P,
                                                 const f16* __restrict__ esWT,
                                                 const float* __restrict__ bm,
                                                 float* __restrict__ e_pre,
                                                 float* __restrict__ stats) {
    __shared__ float s_stats[128];
    int tid = threadIdx.x;
    if (tid < 128) s_stats[tid] = 0.f;
    __syncthreads();
    int lane = tid & 63, wv = tid >> 6;
    int l15 = lane & 15, lk = lane >> 4;
    int rowbase = blockIdx.x * 128 + wv * 32;

    f32x4 acc[2][4];
    #pragma unroll
    for (int mi = 0; mi < 2; mi++)
        #pragma unroll
        for (int ni = 0; ni < 4; ni++)
            acc[mi][ni] = (f32x4){0.f, 0.f, 0.f, 0.f};
    float rs[2] = {0.f, 0.f};

    const float* pr[2];
    pr[0] = P + (size_t)(rowbase + l15) * NI;
    pr[1] = P + (size_t)(rowbase + 16 + l15) * NI;
    const f16* bp[4];
    #pragma unroll
    for (int ni = 0; ni < 4; ni++)
        bp[ni] = esWT + (size_t)(ni * 16 + l15) * KPAD;

    // 12 full K-steps (k = 0..383)
    for (int step = 0; step < 12; step++) {
        int kb = step * 32 + lk * 8;
        f16x8 afr[2];
        #pragma unroll
        for (int mi = 0; mi < 2; mi++) {
            const float* p = pr[mi] + kb;
            float2 q0 = *(const float2*)(p);
            float2 q1 = *(const float2*)(p + 2);
            float2 q2 = *(const float2*)(p + 4);
            float2 q3 = *(const float2*)(p + 6);
            rs[mi] += ((q0.x + q0.y) + (q1.x + q1.y)) + ((q2.x + q2.y) + (q3.x + q3.y));
            f16x8 a;
            a[0] = (f16)q0.x; a[1] = (f16)q0.y; a[2] = (f16)q1.x; a[3] = (f16)q1.y;
            a[4] = (f16)q2.x; a[5] = (f16)q2.y; a[6] = (f16)q3.x; a[7] = (f16)q3.y;
            afr[mi] = a;
        }
        f16x8 bfr[4];
        #pragma unroll
        for (int ni = 0; ni < 4; ni++)
            bfr[ni] = *(const f16x8*)(bp[ni] + kb);
        #pragma unroll
        for (int mi = 0; mi < 2; mi++)
            #pragma unroll
            for (int ni = 0; ni < 4; ni++)
                acc[mi][ni] = __builtin_amdgcn_mfma_f32_16x16x32_f16(
                    afr[mi], bfr[ni], acc[mi][ni], 0, 0, 0);
    }
    // tail step: k = 384..389 valid (lk==0 lanes only), rest zero
    {
        f16x8 afr[2];
        #pragma unroll
        for (int mi = 0; mi < 2; mi++) {
            f16x8 a = (f16x8)(f16)0.f;
            if (lk == 0) {
                const float* p = pr[mi] + 384;
                float2 q0 = *(const float2*)(p);
                float2 q1 = *(const float2*)(p + 2);
                float2 q2 = *(const float2*)(p + 4);
                rs[mi] += ((q0.x + q0.y) + (q1.x + q1.y)) + (q2.x + q2.y);
                a[0] = (f16)q0.x; a[1] = (f16)q0.y; a[2] = (f16)q1.x;
                a[3] = (f16)q1.y; a[4] = (f16)q2.x; a[5] = (f16)q2.y;
            }
            afr[mi] = a;
        }
        f16x8 bfr[4];
        #pragma unroll
        for (int ni = 0; ni < 4; ni++)
            bfr[ni] = *(const f16x8*)(bp[ni] + 384 + lk * 8);  // zero-padded region
        #pragma unroll
        for (int mi = 0; mi < 2; mi++)
            #pragma unroll
            for (int ni = 0; ni < 4; ni++)
                acc[mi][ni] = __builtin_amdgcn_mfma_f32_16x16x32_f16(
                    afr[mi], bfr[ni], acc[mi][ni], 0, 0, 0);
    }

    // full rowsums: combine the 4 lk-groups; then fetch C-layout rows
    #pragma unroll
    for (int mi = 0; mi < 2; mi++) {
        rs[mi] += __shfl_xor(rs[mi], 16);
        rs[mi] += __shfl_xor(rs[mi], 32);
    }
    float rsr[2][4];
    #pragma unroll
    for (int mi = 0; mi < 2; mi++)
        #pragma unroll
        for (int j = 0; j < 4; j++)
            rsr[mi][j] = __shfl(rs[mi], lk * 4 + j);

    float bmv[4];
    #pragma unroll
    for (int ni = 0; ni < 4; ni++) bmv[ni] = bm[ni * 16 + l15];

    // epilogue: v = acc/rs + bm; write e_pre; per-column stats
    #pragma unroll
    for (int ni = 0; ni < 4; ni++) {
        float s = 0.f, q = 0.f;
        #pragma unroll
        for (int mi = 0; mi < 2; mi++) {
            #pragma unroll
            for (int j = 0; j < 4; j++) {
                float v = acc[mi][ni][j] / rsr[mi][j] + bmv[ni];
                int row = rowbase + mi * 16 + lk * 4 + j;
                e_pre[(size_t)row * DD + ni * 16 + l15] = v;
                s += v;
                q = fmaf(v, v, q);
            }
        }
        s += __shfl_xor(s, 16); s += __shfl_xor(s, 32);
        q += __shfl_xor(q, 16); q += __shfl_xor(q, 32);
        if (lk == 0) {
            atomicAdd(&s_stats[ni * 16 + l15], s);
            atomicAdd(&s_stats[64 + ni * 16 + l15], q);
        }
    }
    __syncthreads();
    if (tid < 128) atomicAdd(&stats[tid], s_stats[tid]);
}

// ---------------- BN params ----------------
__global__ void bn_finalize(const float* __restrict__ stats,
                            const float* __restrict__ gamma,
                            const float* __restrict__ beta,
                            float* __restrict__ bn) {
    int t = threadIdx.x;
    if (t < 64) {
        float mu  = stats[t] * (1.0f / 65536.0f);
        float ex2 = stats[64 + t] * (1.0f / 65536.0f);
        float var = ex2 - mu * mu;
        float rstd = 1.0f / sqrtf(var + 1e-5f);
        float sc = rstd * gamma[t];
        bn[t] = sc;
        bn[64 + t] = beta[t] - mu * sc;
    }
}

// ---------------- out = relu(BN(e_pre)) @ eh.T  via f16 MFMA ----------------
__global__ __launch_bounds__(256) void out_mfma(const float* __restrict__ e_pre,
                                                const f16* __restrict__ eh16,
                                                const float* __restrict__ bn,
                                                float* __restrict__ out) {
    int tid = threadIdx.x;
    int lane = tid & 63, wid = tid >> 6;
    int wr = wid >> 1, wc = wid & 1;
    int l15 = lane & 15, lk = lane >> 4;
    int r0 = blockIdx.y * 64 + wr * 32;
    int c0 = blockIdx.x * 64 + wc * 32;

    float sc[2][8], of[2][8];
    #pragma unroll
    for (int ks = 0; ks < 2; ks++) {
        int kb = ks * 32 + lk * 8;
        f32x4 s0 = *(const f32x4*)&bn[kb];
        f32x4 s1 = *(const f32x4*)&bn[kb + 4];
        f32x4 o0 = *(const f32x4*)&bn[64 + kb];
        f32x4 o1 = *(const f32x4*)&bn[64 + kb + 4];
        #pragma unroll
        for (int i = 0; i < 4; i++) {
            sc[ks][i] = s0[i]; sc[ks][4 + i] = s1[i];
            of[ks][i] = o0[i]; of[ks][4 + i] = o1[i];
        }
    }

    f16x8 afr[2][2];
    #pragma unroll
    for (int mi = 0; mi < 2; mi++) {
        const float* pr = e_pre + (size_t)(r0 + mi * 16 + l15) * DD;
        #pragma unroll
        for (int ks = 0; ks < 2; ks++) {
            int kb = ks * 32 + lk * 8;
            f32x4 v0 = *(const f32x4*)&pr[kb];
            f32x4 v1 = *(const f32x4*)&pr[kb + 4];
            f16x8 a;
            #pragma unroll
            for (int i = 0; i < 4; i++) {
                a[i]     = (f16)fmaxf(fmaf(v0[i], sc[ks][i],     of[ks][i]),     0.f);
                a[4 + i] = (f16)fmaxf(fmaf(v1[i], sc[ks][4 + i], of[ks][4 + i]), 0.f);
            }
            afr[mi][ks] = a;
        }
    }

    f16x8 bfr[2][2];
    #pragma unroll
    for (int ni = 0; ni < 2; ni++) {
        const f16* pc = eh16 + (size_t)(c0 + ni * 16 + l15) * DD;
        #pragma unroll
        for (int ks = 0; ks < 2; ks++)
            bfr[ni][ks] = *(const f16x8*)&pc[ks * 32 + lk * 8];
    }

    f32x4 acc[2][2];
    #pragma unroll
    for (int mi = 0; mi < 2; mi++)
        #pragma unroll
        for (int ni = 0; ni < 2; ni++)
            acc[mi][ni] = (f32x4){0.f, 0.f, 0.f, 0.f};

    #pragma unroll
    for (int ks = 0; ks < 2; ks++)
        #pragma unroll
        for (int mi = 0; mi < 2; mi++)
            #pragma unroll
            for (int ni = 0; ni < 2; ni++)
                acc[mi][ni] = __builtin_amdgcn_mfma_f32_16x16x32_f16(
                    afr[mi][ks], bfr[ni][ks], acc[mi][ni], 0, 0, 0);

    #pragma unroll
    for (int mi = 0; mi < 2; mi++) {
        #pragma unroll
        for (int ni = 0; ni < 2; ni++) {
            int col = c0 + ni * 16 + l15;
            if (col < NU) {
                #pragma unroll
                for (int j = 0; j < 4; j++) {
                    int row = r0 + mi * 16 + lk * 4 + j;
                    out[(size_t)row * NU + col] = acc[mi][ni][j];
                }
            }
        }
    }
}

// ---------------- launcher ----------------
extern "C" void kernel_launch(void* const* d_in, const int* in_sizes, int n_in,
                              void* d_out, int out_size, void* d_ws, size_t ws_size,
                              hipStream_t stream) {
    const int*   eSH   = (const int*)d_in[0];
    const float* presc = (const float*)d_in[3];
    const float* shemb = (const float*)d_in[4];
    const float* W1  = (const float*)d_in[5];
    const float* b1  = (const float*)d_in[6];
    const float* W2  = (const float*)d_in[7];
    const float* b2  = (const float*)d_in[8];
    const float* Wp1 = (const float*)d_in[9];
    const float* bp1 = (const float*)d_in[10];
    const float* Wp2 = (const float*)d_in[11];
    const float* bp2 = (const float*)d_in[12];
    const float* Wm  = (const float*)d_in[13];
    const float* bm  = (const float*)d_in[14];
    const float* gam = (const float*)d_in[15];
    const float* bet = (const float*)d_in[16];

    float* ws    = (float*)d_ws;
    float* agg   = ws + OFF_AGG;
    float* cnt   = ws + OFF_CNT;
    float* h1    = ws + OFF_H1;
    float* h2    = ws + OFF_H2;
    f16*   eh16  = (f16*)(ws + OFF_EH);
    float* es    = ws + OFF_ES;
    f16*   esWT  = (f16*)(ws + OFF_ESWT);
    float* stats = ws + OFF_STATS;
    float* bnp   = ws + OFF_BN;
    float* e_pre = ws + OFF_EPRE;
    float* out   = (float*)d_out;

    hipMemsetAsync(agg, 0, (76480 + 1280) * sizeof(float), stream);
    hipMemsetAsync(stats, 0, 128 * sizeof(float), stream);
    hipMemsetAsync(eh16, 0, (size_t)NUPAD * DD * sizeof(f16), stream);
    hipMemsetAsync(esWT, 0, (size_t)DD * KPAD * sizeof(f16), stream);

    agg_kernel<<<25000, 256, 0, stream>>>(eSH, shemb, agg, cnt, 1);
    gcn_transform<<<299, 256, 0, stream>>>(agg, cnt, W1, b1, h1);
    hipMemsetAsync(agg, 0, 76480 * sizeof(float), stream);
    agg_kernel<<<25000, 256, 0, stream>>>(eSH, h1, agg, cnt, 0);
    gcn_transform<<<299, 256, 0, stream>>>(agg, cnt, W2, b2, h2);
    proj_kernel<<<299, 256, 0, stream>>>(h2, Wp1, bp1, Wp2, bp2, eh16, es);
    projm_kernel<<<98, 256, 0, stream>>>(es, Wm, esWT);
    synd_mfma<<<512, 256, 0, stream>>>(presc, esWT, bm, e_pre, stats);
    bn_finalize<<<1, 64, 0, stream>>>(stats, gam, bet, bnp);
    out_mfma<<<dim3(13, 1024), 256, 0, stream>>>(e_pre, eh16, bnp, out);
}

// Round 4
// 231.742 us; speedup vs baseline: 1.8506x; 1.1840x over previous
//
#include <hip/hip_runtime.h>
#include <math.h>

#define NSH 1195
#define NU  805
#define NI  390
#define DD  64
#define BROWS 65536
#define ESH 100000
#define KPAD 416   // 13*32
#define NUPAD 832  // 13*64, eh16 padded rows

typedef _Float16 f16;
typedef _Float16 f16x8 __attribute__((ext_vector_type(8)));
typedef float f32x4 __attribute__((ext_vector_type(4)));

// ---------------- ws layout (floats) ----------------
#define OFF_AGG   0u          // 76480
#define OFF_CNT   76480u      // 1280 (padded)
#define OFF_H1    77760u      // 76480
#define OFF_H2    154240u     // 76480
#define OFF_EH    230720u     // eh16: 832*64 f16
#define OFF_ES    282240u     // 24960
#define OFF_ESWT  307200u     // esWT16: 64*416 f16
#define OFF_STATS 332160u     // 128
#define OFF_BN    332288u     // 128 (unused now)
#define OFF_EPRE  332416u     // 4194304

// ---------------- GCN aggregate ----------------
__global__ __launch_bounds__(256) void agg_kernel(const int* __restrict__ edges,
                                                  const float* __restrict__ x,
                                                  float* __restrict__ agg,
                                                  float* __restrict__ cnt,
                                                  int do_cnt) {
    int gid = blockIdx.x * 256 + threadIdx.x;
    int e = gid >> 6;
    int d = gid & 63;
    if (e < ESH) {
        int s = edges[e];
        int t = edges[ESH + e];
        atomicAdd(&agg[t * DD + d], x[s * DD + d]);
        if (do_cnt && d == 0) atomicAdd(&cnt[t], 1.0f);
    }
}

// ---------------- GCN transform ----------------
__global__ __launch_bounds__(256) void gcn_transform(const float* __restrict__ agg,
                                                     const float* __restrict__ cnt,
                                                     const float* __restrict__ W,
                                                     const float* __restrict__ b,
                                                     float* __restrict__ out) {
    __shared__ float s_wt[DD * DD];
    __shared__ float s_z[4 * DD];
    int tid = threadIdx.x;
    for (int i = tid; i < DD * DD; i += 256) {
        int j = i >> 6, k = i & 63;
        s_wt[k * DD + j] = W[i];
    }
    int w = tid >> 6, j = tid & 63;
    int node = blockIdx.x * 4 + w;
    bool active = node < NSH;
    s_z[w * DD + j] = active ? agg[node * DD + j] : 0.f;
    __syncthreads();
    float c = active ? cnt[node] : 0.f;
    float acc = c * b[j];
    #pragma unroll 8
    for (int k = 0; k < DD; k++)
        acc = fmaf(s_z[w * DD + k], s_wt[k * DD + j], acc);
    float h = tanhf(acc / fmaxf(c, 1.0f));
    if (active) out[node * DD + j] = h;
}

// ---------------- proj + l2norm: es (f32) / eh (f16) ----------------
__global__ __launch_bounds__(256) void proj_kernel(const float* __restrict__ h2,
                                                   const float* __restrict__ Wp1,
                                                   const float* __restrict__ bp1,
                                                   const float* __restrict__ Wp2,
                                                   const float* __restrict__ bp2,
                                                   f16* __restrict__ eh16,
                                                   float* __restrict__ es) {
    __shared__ float s_w1[DD * DD], s_w2[DD * DD];
    __shared__ float s_z[4 * DD], s_t[4 * DD];
    int tid = threadIdx.x;
    for (int i = tid; i < DD * DD; i += 256) {
        int j = i >> 6, k = i & 63;
        s_w1[k * DD + j] = Wp1[i];
        s_w2[k * DD + j] = Wp2[i];
    }
    int w = tid >> 6, j = tid & 63;
    int node = blockIdx.x * 4 + w;
    bool active = node < NSH;
    s_z[w * DD + j] = active ? h2[node * DD + j] : 0.f;
    __syncthreads();
    float acc = bp1[j];
    #pragma unroll 8
    for (int k = 0; k < DD; k++)
        acc = fmaf(s_z[w * DD + k], s_w1[k * DD + j], acc);
    float t = acc > 0.f ? acc : expm1f(acc);
    s_t[w * DD + j] = t;
    __syncthreads();
    float o = bp2[j];
    #pragma unroll 8
    for (int k = 0; k < DD; k++)
        o = fmaf(s_t[w * DD + k], s_w2[k * DD + j], o);
    float sq = o * o;
    #pragma unroll
    for (int off = 1; off < 64; off <<= 1) sq += __shfl_xor(sq, off);
    float r = o / sqrtf(sq);
    if (active) {
        if (node < NU) eh16[node * DD + j] = (f16)r;
        else           es[(node - NU) * DD + j] = r;
    }
}

// ---------------- esWT16[n][k] = (es @ Wm.T)[k][n] as f16, K padded ----------------
__global__ __launch_bounds__(256) void projm_kernel(const float* __restrict__ es,
                                                    const float* __restrict__ Wm,
                                                    f16* __restrict__ esWT) {
    __shared__ float s_wt[DD * DD];
    __shared__ float s_z[4 * DD];
    int tid = threadIdx.x;
    for (int i = tid; i < DD * DD; i += 256) {
        int j = i >> 6, k = i & 63;
        s_wt[k * DD + j] = Wm[i];
    }
    int w = tid >> 6, j = tid & 63;
    int r = blockIdx.x * 4 + w;
    bool active = r < NI;
    s_z[w * DD + j] = active ? es[r * DD + j] : 0.f;
    __syncthreads();
    float o = 0.f;
    #pragma unroll 8
    for (int k = 0; k < DD; k++)
        o = fmaf(s_z[w * DD + k], s_wt[k * DD + j], o);
    if (active) esWT[j * KPAD + r] = (f16)o;
}

// ---------------- e_pre = (P @ esW)/rowsum(P) + bm via f16 MFMA; BN stats ----------------
__global__ __launch_bounds__(256) void synd_mfma(const float* __restrict__ P,
                                                 const f16* __restrict__ esWT,
                                                 const float* __restrict__ bm,
                                                 float* __restrict__ e_pre,
                                                 float* __restrict__ stats) {
    __shared__ float s_stats[128];
    int tid = threadIdx.x;
    if (tid < 128) s_stats[tid] = 0.f;
    __syncthreads();
    int lane = tid & 63, wv = tid >> 6;
    int l15 = lane & 15, lk = lane >> 4;
    int rowbase = blockIdx.x * 128 + wv * 32;

    f32x4 acc[2][4];
    #pragma unroll
    for (int mi = 0; mi < 2; mi++)
        #pragma unroll
        for (int ni = 0; ni < 4; ni++)
            acc[mi][ni] = (f32x4){0.f, 0.f, 0.f, 0.f};
    float rs[2] = {0.f, 0.f};

    const float* pr[2];
    pr[0] = P + (size_t)(rowbase + l15) * NI;
    pr[1] = P + (size_t)(rowbase + 16 + l15) * NI;
    const f16* bp[4];
    #pragma unroll
    for (int ni = 0; ni < 4; ni++)
        bp[ni] = esWT + (size_t)(ni * 16 + l15) * KPAD;

    for (int step = 0; step < 12; step++) {
        int kb = step * 32 + lk * 8;
        f16x8 afr[2];
        #pragma unroll
        for (int mi = 0; mi < 2; mi++) {
            const float* p = pr[mi] + kb;
            float2 q0 = *(const float2*)(p);
            float2 q1 = *(const float2*)(p + 2);
            float2 q2 = *(const float2*)(p + 4);
            float2 q3 = *(const float2*)(p + 6);
            rs[mi] += ((q0.x + q0.y) + (q1.x + q1.y)) + ((q2.x + q2.y) + (q3.x + q3.y));
            f16x8 a;
            a[0] = (f16)q0.x; a[1] = (f16)q0.y; a[2] = (f16)q1.x; a[3] = (f16)q1.y;
            a[4] = (f16)q2.x; a[5] = (f16)q2.y; a[6] = (f16)q3.x; a[7] = (f16)q3.y;
            afr[mi] = a;
        }
        f16x8 bfr[4];
        #pragma unroll
        for (int ni = 0; ni < 4; ni++)
            bfr[ni] = *(const f16x8*)(bp[ni] + kb);
        #pragma unroll
        for (int mi = 0; mi < 2; mi++)
            #pragma unroll
            for (int ni = 0; ni < 4; ni++)
                acc[mi][ni] = __builtin_amdgcn_mfma_f32_16x16x32_f16(
                    afr[mi], bfr[ni], acc[mi][ni], 0, 0, 0);
    }
    {
        f16x8 afr[2];
        #pragma unroll
        for (int mi = 0; mi < 2; mi++) {
            f16x8 a = (f16x8)(f16)0.f;
            if (lk == 0) {
                const float* p = pr[mi] + 384;
                float2 q0 = *(const float2*)(p);
                float2 q1 = *(const float2*)(p + 2);
                float2 q2 = *(const float2*)(p + 4);
                rs[mi] += ((q0.x + q0.y) + (q1.x + q1.y)) + (q2.x + q2.y);
                a[0] = (f16)q0.x; a[1] = (f16)q0.y; a[2] = (f16)q1.x;
                a[3] = (f16)q1.y; a[4] = (f16)q2.x; a[5] = (f16)q2.y;
            }
            afr[mi] = a;
        }
        f16x8 bfr[4];
        #pragma unroll
        for (int ni = 0; ni < 4; ni++)
            bfr[ni] = *(const f16x8*)(bp[ni] + 384 + lk * 8);
        #pragma unroll
        for (int mi = 0; mi < 2; mi++)
            #pragma unroll
            for (int ni = 0; ni < 4; ni++)
                acc[mi][ni] = __builtin_amdgcn_mfma_f32_16x16x32_f16(
                    afr[mi], bfr[ni], acc[mi][ni], 0, 0, 0);
    }

    #pragma unroll
    for (int mi = 0; mi < 2; mi++) {
        rs[mi] += __shfl_xor(rs[mi], 16);
        rs[mi] += __shfl_xor(rs[mi], 32);
    }
    float rsr[2][4];
    #pragma unroll
    for (int mi = 0; mi < 2; mi++)
        #pragma unroll
        for (int j = 0; j < 4; j++)
            rsr[mi][j] = __shfl(rs[mi], lk * 4 + j);

    float bmv[4];
    #pragma unroll
    for (int ni = 0; ni < 4; ni++) bmv[ni] = bm[ni * 16 + l15];

    #pragma unroll
    for (int ni = 0; ni < 4; ni++) {
        float s = 0.f, q = 0.f;
        #pragma unroll
        for (int mi = 0; mi < 2; mi++) {
            #pragma unroll
            for (int j = 0; j < 4; j++) {
                float v = acc[mi][ni][j] / rsr[mi][j] + bmv[ni];
                int row = rowbase + mi * 16 + lk * 4 + j;
                e_pre[(size_t)row * DD + ni * 16 + l15] = v;
                s += v;
                q = fmaf(v, v, q);
            }
        }
        s += __shfl_xor(s, 16); s += __shfl_xor(s, 32);
        q += __shfl_xor(q, 16); q += __shfl_xor(q, 32);
        if (lk == 0) {
            atomicAdd(&s_stats[ni * 16 + l15], s);
            atomicAdd(&s_stats[64 + ni * 16 + l15], q);
        }
    }
    __syncthreads();
    if (tid < 128) atomicAdd(&stats[tid], s_stats[tid]);
}

// ---------------- out = relu(BN(e_pre)) @ eh.T : col-grouped, e_pre read once ----------------
// blockIdx.x: col-group (0: cols 0..447 = 7 tiles; 1: cols 448..831 = 6 tiles)
// blockIdx.y: 64-row slab. 4 waves, 16 rows each. eh16 group staged in LDS
// with 16B-slot XOR swizzle (slot ^= col&7) -> conflict-free ds_read_b128.
#define CG0 448
__global__ __launch_bounds__(256) void out_fused(const float* __restrict__ e_pre,
                                                 const f16* __restrict__ eh16,
                                                 const float* __restrict__ stats,
                                                 const float* __restrict__ gamma,
                                                 const float* __restrict__ beta,
                                                 float* __restrict__ out) {
    __shared__ __align__(16) f16 s_eh[CG0 * DD];   // 57344 B
    __shared__ float s_bn[128];
    int tid = threadIdx.x;
    int cg = blockIdx.x;
    int nrows = cg == 0 ? CG0 : (NUPAD - CG0);   // 448 / 384
    int cbase = cg * CG0;

    // BN params in-block
    if (tid < 64) {
        float mu  = stats[tid] * (1.0f / 65536.0f);
        float ex2 = stats[64 + tid] * (1.0f / 65536.0f);
        float var = ex2 - mu * mu;
        float rstd = 1.0f / sqrtf(var + 1e-5f);
        float sc = rstd * gamma[tid];
        s_bn[tid] = sc;
        s_bn[64 + tid] = beta[tid] - mu * sc;
    }

    // stage eh16 col-group, swizzled: 16B chunk (row, slot) -> slot^(row&7)
    const uint4* src = (const uint4*)(eh16 + (size_t)cbase * DD);
    int nchunks = nrows * 8;
    for (int c = tid; c < nchunks; c += 256) {
        int row = c >> 3, slot = c & 7;
        uint4 v = src[c];
        *(uint4*)&s_eh[row * DD + ((slot ^ (row & 7)) << 3)] = v;
    }
    __syncthreads();

    int lane = tid & 63, w = tid >> 6;
    int l15 = lane & 15, lk = lane >> 4;
    int r0 = blockIdx.y * 64 + w * 16;

    // A fragments: load e_pre row once, BN+relu+f16, reused for all col-tiles
    f16x8 afr[2];
    {
        const float* pr = e_pre + (size_t)(r0 + l15) * DD;
        #pragma unroll
        for (int ks = 0; ks < 2; ks++) {
            int kb = ks * 32 + lk * 8;
            f32x4 v0 = *(const f32x4*)&pr[kb];
            f32x4 v1 = *(const f32x4*)&pr[kb + 4];
            f16x8 a;
            #pragma unroll
            for (int i = 0; i < 4; i++) {
                a[i]     = (f16)fmaxf(fmaf(v0[i], s_bn[kb + i],     s_bn[64 + kb + i]),     0.f);
                a[4 + i] = (f16)fmaxf(fmaf(v1[i], s_bn[kb + 4 + i], s_bn[64 + kb + 4 + i]), 0.f);
            }
            afr[ks] = a;
        }
    }

    int nt = cg == 0 ? 7 : 6;
    for (int cb = 0; cb < nt; cb += 4) {
        f32x4 acc[4][4];
        #pragma unroll
        for (int tt = 0; tt < 4; tt++)
            #pragma unroll
            for (int c16 = 0; c16 < 4; c16++)
                acc[tt][c16] = (f32x4){0.f, 0.f, 0.f, 0.f};

        #pragma unroll
        for (int tt = 0; tt < 4; tt++) {
            if (cb + tt < nt) {
                #pragma unroll
                for (int c16 = 0; c16 < 4; c16++) {
                    int lc = (cb + tt) * 64 + c16 * 16 + l15;
                    #pragma unroll
                    for (int ks = 0; ks < 2; ks++) {
                        int slot = (ks * 4 + lk) ^ (lc & 7);
                        f16x8 b = *(const f16x8*)&s_eh[lc * DD + (slot << 3)];
                        acc[tt][c16] = __builtin_amdgcn_mfma_f32_16x16x32_f16(
                            afr[ks], b, acc[tt][c16], 0, 0, 0);
                    }
                }
            }
        }
        #pragma unroll
        for (int tt = 0; tt < 4; tt++) {
            if (cb + tt < nt) {
                #pragma unroll
                for (int c16 = 0; c16 < 4; c16++) {
                    int col = cbase + (cb + tt) * 64 + c16 * 16 + l15;
                    if (col < NU) {
                        #pragma unroll
                        for (int j = 0; j < 4; j++) {
                            int row = r0 + lk * 4 + j;
                            out[(size_t)row * NU + col] = acc[tt][c16][j];
                        }
                    }
                }
            }
        }
    }
}

// ---------------- launcher ----------------
extern "C" void kernel_launch(void* const* d_in, const int* in_sizes, int n_in,
                              void* d_out, int out_size, void* d_ws, size_t ws_size,
                              hipStream_t stream) {
    const int*   eSH   = (const int*)d_in[0];
    const float* presc = (const float*)d_in[3];
    const float* shemb = (const float*)d_in[4];
    const float* W1  = (const float*)d_in[5];
    const float* b1  = (const float*)d_in[6];
    const float* W2  = (const float*)d_in[7];
    const float* b2  = (const float*)d_in[8];
    const float* Wp1 = (const float*)d_in[9];
    const float* bp1 = (const float*)d_in[10];
    const float* Wp2 = (const float*)d_in[11];
    const float* bp2 = (const float*)d_in[12];
    const float* Wm  = (const float*)d_in[13];
    const float* bm  = (const float*)d_in[14];
    const float* gam = (const float*)d_in[15];
    const float* bet = (const float*)d_in[16];

    float* ws    = (float*)d_ws;
    float* agg   = ws + OFF_AGG;
    float* cnt   = ws + OFF_CNT;
    float* h1    = ws + OFF_H1;
    float* h2    = ws + OFF_H2;
    f16*   eh16  = (f16*)(ws + OFF_EH);
    float* es    = ws + OFF_ES;
    f16*   esWT  = (f16*)(ws + OFF_ESWT);
    float* stats = ws + OFF_STATS;
    float* e_pre = ws + OFF_EPRE;
    float* out   = (float*)d_out;

    hipMemsetAsync(agg, 0, (76480 + 1280) * sizeof(float), stream);
    hipMemsetAsync(stats, 0, 128 * sizeof(float), stream);
    hipMemsetAsync(eh16, 0, (size_t)NUPAD * DD * sizeof(f16), stream);
    hipMemsetAsync(esWT, 0, (size_t)DD * KPAD * sizeof(f16), stream);

    agg_kernel<<<25000, 256, 0, stream>>>(eSH, shemb, agg, cnt, 1);
    gcn_transform<<<299, 256, 0, stream>>>(agg, cnt, W1, b1, h1);
    hipMemsetAsync(agg, 0, 76480 * sizeof(float), stream);
    agg_kernel<<<25000, 256, 0, stream>>>(eSH, h1, agg, cnt, 0);
    gcn_transform<<<299, 256, 0, stream>>>(agg, cnt, W2, b2, h2);
    proj_kernel<<<299, 256, 0, stream>>>(h2, Wp1, bp1, Wp2, bp2, eh16, es);
    projm_kernel<<<98, 256, 0, stream>>>(es, Wm, esWT);
    synd_mfma<<<512, 256, 0, stream>>>(presc, esWT, bm, e_pre, stats);
    out_fused<<<dim3(2, 1024), 256, 0, stream>>>(e_pre, eh16, stats, gam, bet, out);
}

// Round 5
// 230.981 us; speedup vs baseline: 1.8567x; 1.0033x over previous
//
#include <hip/hip_runtime.h>
#include <math.h>

#define NSH 1195
#define NU  805
#define NI  390
#define DD  64
#define BROWS 65536
#define ESH 100000
#define KPAD 416   // 13*32
#define NUPAD 832  // 13*64, eh16 padded rows

typedef _Float16 f16;
typedef _Float16 f16x8 __attribute__((ext_vector_type(8)));
typedef float f32x4 __attribute__((ext_vector_type(4)));

// ---------------- ws layout (float units) ----------------
// zeroed-every-call region (one memset): [stats | esWT | eh16 | hist]
#define OFF_STATS  0u        // 128
#define OFF_ESWT   128u      // 64*416 f16 = 13312 floats
#define OFF_EH     13440u    // 832*64 f16 = 26624 floats
#define OFF_HIST   40064u    // 1280 ints
#define ZERO_FLOATS 41344u
#define OFF_ROWPTR 41344u    // 1280 ints
#define OFF_CURSOR 42624u    // 1280 ints
#define OFF_COLIDX 43904u    // 100096 ints
#define OFF_H1     144000u   // 76480
#define OFF_EPRE   220480u   // 4194304
// total = 4414784 floats = 17.7 MB

// ---------------- CSR build ----------------
__global__ __launch_bounds__(256) void hist_kernel(const int* __restrict__ edges,
                                                   int* __restrict__ hist) {
    int e = blockIdx.x * 256 + threadIdx.x;
    if (e < ESH) atomicAdd(&hist[edges[ESH + e]], 1);
}

__global__ __launch_bounds__(1024) void scan_kernel(const int* __restrict__ hist,
                                                    int* __restrict__ row_ptr,
                                                    int* __restrict__ cursor) {
    __shared__ int s[2048];
    int t = threadIdx.x;
    s[t] = (t < NSH) ? hist[t] : 0;
    s[t + 1024] = (t + 1024 < NSH) ? hist[t + 1024] : 0;
    __syncthreads();
    for (int off = 1; off < 2048; off <<= 1) {
        int a = s[t], b = s[t + 1024];
        int aa = (t >= off) ? s[t - off] : 0;
        int bb = s[t + 1024 - off];
        __syncthreads();
        s[t] = a + aa;
        s[t + 1024] = b + bb;
        __syncthreads();
    }
    if (t == 0) row_ptr[0] = 0;
    for (int i = t; i < NSH; i += 1024) {
        row_ptr[i + 1] = s[i];
        cursor[i] = (i == 0) ? 0 : s[i - 1];
    }
}

__global__ __launch_bounds__(256) void scatter_kernel(const int* __restrict__ edges,
                                                      int* __restrict__ cursor,
                                                      int* __restrict__ col_idx) {
    int e = blockIdx.x * 256 + threadIdx.x;
    if (e < ESH) {
        int t = edges[ESH + e];
        int pos = atomicAdd(&cursor[t], 1);
        col_idx[pos] = edges[e];
    }
}

// ---------------- layer 1: gather + transform, one block per node ----------------
__global__ __launch_bounds__(256) void gcn_gather1(const int* __restrict__ row_ptr,
                                                   const int* __restrict__ col_idx,
                                                   const float* __restrict__ x,
                                                   const float* __restrict__ W,
                                                   const float* __restrict__ b,
                                                   float* __restrict__ out) {
    __shared__ float s_wt[DD * DD];
    __shared__ float s_p[4 * DD];
    int tid = threadIdx.x;
    int w = tid >> 6, lane = tid & 63;
    for (int i = tid; i < DD * DD; i += 256) {
        int j = i >> 6, k = i & 63;
        s_wt[k * DD + j] = W[i];
    }
    int node = blockIdx.x;
    int beg = row_ptr[node], end = row_ptr[node + 1];
    float acc = 0.f;
    for (int e = beg + w; e < end; e += 4)
        acc += x[col_idx[e] * DD + lane];
    s_p[w * DD + lane] = acc;
    __syncthreads();
    float z = s_p[lane] + s_p[DD + lane] + s_p[2 * DD + lane] + s_p[3 * DD + lane];
    __syncthreads();
    if (w == 0) s_p[lane] = z;
    __syncthreads();
    float cntf = (float)(end - beg);
    float o = cntf * b[lane];
    #pragma unroll 8
    for (int k = 0; k < DD; k++)
        o = fmaf(s_p[k], s_wt[k * DD + lane], o);
    float h = tanhf(o / fmaxf(cntf, 1.f));
    if (w == 0) out[node * DD + lane] = h;
}

// ---------------- layer 2 fused: gather + transform + proj + l2n + (Wm for i-nodes) ----------------
__global__ __launch_bounds__(256) void gcn2_fused(const int* __restrict__ row_ptr,
                                                  const int* __restrict__ col_idx,
                                                  const float* __restrict__ h1,
                                                  const float* __restrict__ W2,
                                                  const float* __restrict__ b2,
                                                  const float* __restrict__ Wp1,
                                                  const float* __restrict__ bp1,
                                                  const float* __restrict__ Wp2,
                                                  const float* __restrict__ bp2,
                                                  const float* __restrict__ Wm,
                                                  f16* __restrict__ eh16,
                                                  f16* __restrict__ esWT) {
    __shared__ float s_w2[DD * DD], s_p1[DD * DD], s_p2[DD * DD], s_wm[DD * DD];
    __shared__ float s_v[4 * DD];
    int tid = threadIdx.x;
    int w = tid >> 6, lane = tid & 63;
    for (int i = tid; i < DD * DD; i += 256) {
        int j = i >> 6, k = i & 63;
        s_w2[k * DD + j] = W2[i];
        s_p1[k * DD + j] = Wp1[i];
        s_p2[k * DD + j] = Wp2[i];
        s_wm[k * DD + j] = Wm[i];
    }
    int node = blockIdx.x;
    int beg = row_ptr[node], end = row_ptr[node + 1];
    float acc = 0.f;
    for (int e = beg + w; e < end; e += 4)
        acc += h1[col_idx[e] * DD + lane];
    s_v[w * DD + lane] = acc;
    __syncthreads();
    float z = s_v[lane] + s_v[DD + lane] + s_v[2 * DD + lane] + s_v[3 * DD + lane];
    __syncthreads();
    if (w == 0) s_v[lane] = z;
    __syncthreads();
    // h2 = tanh((z@W2.T + cnt*b2)/max(cnt,1))
    float cntf = (float)(end - beg);
    float o = cntf * b2[lane];
    #pragma unroll 8
    for (int k = 0; k < DD; k++)
        o = fmaf(s_v[k], s_w2[k * DD + lane], o);
    float h2v = tanhf(o / fmaxf(cntf, 1.f));
    __syncthreads();
    if (w == 0) s_v[lane] = h2v;
    __syncthreads();
    // t = elu(h2 @ Wp1.T + bp1)
    float t = bp1[lane];
    #pragma unroll 8
    for (int k = 0; k < DD; k++)
        t = fmaf(s_v[k], s_p1[k * DD + lane], t);
    t = t > 0.f ? t : expm1f(t);
    __syncthreads();
    if (w == 0) s_v[lane] = t;
    __syncthreads();
    // o2 = t @ Wp2.T + bp2 ; r = l2n(o2)
    float o2 = bp2[lane];
    #pragma unroll 8
    for (int k = 0; k < DD; k++)
        o2 = fmaf(s_v[k], s_p2[k * DD + lane], o2);
    float sq = o2 * o2;
    #pragma unroll
    for (int off = 1; off < 64; off <<= 1) sq += __shfl_xor(sq, off);
    float r = o2 / sqrtf(sq);
    if (node < NU) {
        if (w == 0) eh16[node * DD + lane] = (f16)r;
    } else {
        __syncthreads();
        if (w == 0) s_v[lane] = r;
        __syncthreads();
        float m = 0.f;
        #pragma unroll 8
        for (int k = 0; k < DD; k++)
            m = fmaf(s_v[k], s_wm[k * DD + lane], m);
        if (w == 0) esWT[lane * KPAD + (node - NU)] = (f16)m;
    }
}

// ---------------- e_pre = (P @ esW)/rowsum(P) + bm via f16 MFMA; BN stats ----------------
__global__ __launch_bounds__(256) void synd_mfma(const float* __restrict__ P,
                                                 const f16* __restrict__ esWT,
                                                 const float* __restrict__ bm,
                                                 float* __restrict__ e_pre,
                                                 float* __restrict__ stats) {
    __shared__ float s_stats[128];
    int tid = threadIdx.x;
    if (tid < 128) s_stats[tid] = 0.f;
    __syncthreads();
    int lane = tid & 63, wv = tid >> 6;
    int l15 = lane & 15, lk = lane >> 4;
    int rowbase = blockIdx.x * 128 + wv * 32;

    f32x4 acc[2][4];
    #pragma unroll
    for (int mi = 0; mi < 2; mi++)
        #pragma unroll
        for (int ni = 0; ni < 4; ni++)
            acc[mi][ni] = (f32x4){0.f, 0.f, 0.f, 0.f};
    float rs[2] = {0.f, 0.f};

    const float* pr[2];
    pr[0] = P + (size_t)(rowbase + l15) * NI;
    pr[1] = P + (size_t)(rowbase + 16 + l15) * NI;
    const f16* bp[4];
    #pragma unroll
    for (int ni = 0; ni < 4; ni++)
        bp[ni] = esWT + (size_t)(ni * 16 + l15) * KPAD;

    for (int step = 0; step < 12; step++) {
        int kb = step * 32 + lk * 8;
        f16x8 afr[2];
        #pragma unroll
        for (int mi = 0; mi < 2; mi++) {
            const float* p = pr[mi] + kb;
            float2 q0 = *(const float2*)(p);
            float2 q1 = *(const float2*)(p + 2);
            float2 q2 = *(const float2*)(p + 4);
            float2 q3 = *(const float2*)(p + 6);
            rs[mi] += ((q0.x + q0.y) + (q1.x + q1.y)) + ((q2.x + q2.y) + (q3.x + q3.y));
            f16x8 a;
            a[0] = (f16)q0.x; a[1] = (f16)q0.y; a[2] = (f16)q1.x; a[3] = (f16)q1.y;
            a[4] = (f16)q2.x; a[5] = (f16)q2.y; a[6] = (f16)q3.x; a[7] = (f16)q3.y;
            afr[mi] = a;
        }
        f16x8 bfr[4];
        #pragma unroll
        for (int ni = 0; ni < 4; ni++)
            bfr[ni] = *(const f16x8*)(bp[ni] + kb);
        #pragma unroll
        for (int mi = 0; mi < 2; mi++)
            #pragma unroll
            for (int ni = 0; ni < 4; ni++)
                acc[mi][ni] = __builtin_amdgcn_mfma_f32_16x16x32_f16(
                    afr[mi], bfr[ni], acc[mi][ni], 0, 0, 0);
    }
    {
        f16x8 afr[2];
        #pragma unroll
        for (int mi = 0; mi < 2; mi++) {
            f16x8 a = (f16x8)(f16)0.f;
            if (lk == 0) {
                const float* p = pr[mi] + 384;
                float2 q0 = *(const float2*)(p);
                float2 q1 = *(const float2*)(p + 2);
                float2 q2 = *(const float2*)(p + 4);
                rs[mi] += ((q0.x + q0.y) + (q1.x + q1.y)) + (q2.x + q2.y);
                a[0] = (f16)q0.x; a[1] = (f16)q0.y; a[2] = (f16)q1.x;
                a[3] = (f16)q1.y; a[4] = (f16)q2.x; a[5] = (f16)q2.y;
            }
            afr[mi] = a;
        }
        f16x8 bfr[4];
        #pragma unroll
        for (int ni = 0; ni < 4; ni++)
            bfr[ni] = *(const f16x8*)(bp[ni] + 384 + lk * 8);
        #pragma unroll
        for (int mi = 0; mi < 2; mi++)
            #pragma unroll
            for (int ni = 0; ni < 4; ni++)
                acc[mi][ni] = __builtin_amdgcn_mfma_f32_16x16x32_f16(
                    afr[mi], bfr[ni], acc[mi][ni], 0, 0, 0);
    }

    #pragma unroll
    for (int mi = 0; mi < 2; mi++) {
        rs[mi] += __shfl_xor(rs[mi], 16);
        rs[mi] += __shfl_xor(rs[mi], 32);
    }
    float rsr[2][4];
    #pragma unroll
    for (int mi = 0; mi < 2; mi++)
        #pragma unroll
        for (int j = 0; j < 4; j++)
            rsr[mi][j] = __shfl(rs[mi], lk * 4 + j);

    float bmv[4];
    #pragma unroll
    for (int ni = 0; ni < 4; ni++) bmv[ni] = bm[ni * 16 + l15];

    #pragma unroll
    for (int ni = 0; ni < 4; ni++) {
        float s = 0.f, q = 0.f;
        #pragma unroll
        for (int mi = 0; mi < 2; mi++) {
            #pragma unroll
            for (int j = 0; j < 4; j++) {
                float v = acc[mi][ni][j] / rsr[mi][j] + bmv[ni];
                int row = rowbase + mi * 16 + lk * 4 + j;
                e_pre[(size_t)row * DD + ni * 16 + l15] = v;
                s += v;
                q = fmaf(v, v, q);
            }
        }
        s += __shfl_xor(s, 16); s += __shfl_xor(s, 32);
        q += __shfl_xor(q, 16); q += __shfl_xor(q, 32);
        if (lk == 0) {
            atomicAdd(&s_stats[ni * 16 + l15], s);
            atomicAdd(&s_stats[64 + ni * 16 + l15], q);
        }
    }
    __syncthreads();
    if (tid < 128) atomicAdd(&stats[tid], s_stats[tid]);
}

// ---------------- out = relu(BN(e_pre)) @ eh.T : col-grouped, e_pre read once ----------------
#define CG0 448
__global__ __launch_bounds__(256) void out_fused(const float* __restrict__ e_pre,
                                                 const f16* __restrict__ eh16,
                                                 const float* __restrict__ stats,
                                                 const float* __restrict__ gamma,
                                                 const float* __restrict__ beta,
                                                 float* __restrict__ out) {
    __shared__ __align__(16) f16 s_eh[CG0 * DD];
    __shared__ float s_bn[128];
    int tid = threadIdx.x;
    int cg = blockIdx.x;
    int nrows = cg == 0 ? CG0 : (NUPAD - CG0);
    int cbase = cg * CG0;

    if (tid < 64) {
        float mu  = stats[tid] * (1.0f / 65536.0f);
        float ex2 = stats[64 + tid] * (1.0f / 65536.0f);
        float var = ex2 - mu * mu;
        float rstd = 1.0f / sqrtf(var + 1e-5f);
        float sc = rstd * gamma[tid];
        s_bn[tid] = sc;
        s_bn[64 + tid] = beta[tid] - mu * sc;
    }

    const uint4* src = (const uint4*)(eh16 + (size_t)cbase * DD);
    int nchunks = nrows * 8;
    for (int c = tid; c < nchunks; c += 256) {
        int row = c >> 3, slot = c & 7;
        uint4 v = src[c];
        *(uint4*)&s_eh[row * DD + ((slot ^ (row & 7)) << 3)] = v;
    }
    __syncthreads();

    int lane = tid & 63, w = tid >> 6;
    int l15 = lane & 15, lk = lane >> 4;
    int r0 = blockIdx.y * 64 + w * 16;

    f16x8 afr[2];
    {
        const float* pr = e_pre + (size_t)(r0 + l15) * DD;
        #pragma unroll
        for (int ks = 0; ks < 2; ks++) {
            int kb = ks * 32 + lk * 8;
            f32x4 v0 = *(const f32x4*)&pr[kb];
            f32x4 v1 = *(const f32x4*)&pr[kb + 4];
            f16x8 a;
            #pragma unroll
            for (int i = 0; i < 4; i++) {
                a[i]     = (f16)fmaxf(fmaf(v0[i], s_bn[kb + i],     s_bn[64 + kb + i]),     0.f);
                a[4 + i] = (f16)fmaxf(fmaf(v1[i], s_bn[kb + 4 + i], s_bn[64 + kb + 4 + i]), 0.f);
            }
            afr[ks] = a;
        }
    }

    int nt = cg == 0 ? 7 : 6;
    for (int cb = 0; cb < nt; cb += 4) {
        f32x4 acc[4][4];
        #pragma unroll
        for (int tt = 0; tt < 4; tt++)
            #pragma unroll
            for (int c16 = 0; c16 < 4; c16++)
                acc[tt][c16] = (f32x4){0.f, 0.f, 0.f, 0.f};

        #pragma unroll
        for (int tt = 0; tt < 4; tt++) {
            if (cb + tt < nt) {
                #pragma unroll
                for (int c16 = 0; c16 < 4; c16++) {
                    int lc = (cb + tt) * 64 + c16 * 16 + l15;
                    #pragma unroll
                    for (int ks = 0; ks < 2; ks++) {
                        int slot = (ks * 4 + lk) ^ (lc & 7);
                        f16x8 b = *(const f16x8*)&s_eh[lc * DD + (slot << 3)];
                        acc[tt][c16] = __builtin_amdgcn_mfma_f32_16x16x32_f16(
                            afr[ks], b, acc[tt][c16], 0, 0, 0);
                    }
                }
            }
        }
        #pragma unroll
        for (int tt = 0; tt < 4; tt++) {
            if (cb + tt < nt) {
                #pragma unroll
                for (int c16 = 0; c16 < 4; c16++) {
                    int col = cbase + (cb + tt) * 64 + c16 * 16 + l15;
                    if (col < NU) {
                        #pragma unroll
                        for (int j = 0; j < 4; j++) {
                            int row = r0 + lk * 4 + j;
                            out[(size_t)row * NU + col] = acc[tt][c16][j];
                        }
                    }
                }
            }
        }
    }
}

// ---------------- launcher ----------------
extern "C" void kernel_launch(void* const* d_in, const int* in_sizes, int n_in,
                              void* d_out, int out_size, void* d_ws, size_t ws_size,
                              hipStream_t stream) {
    const int*   eSH   = (const int*)d_in[0];
    const float* presc = (const float*)d_in[3];
    const float* shemb = (const float*)d_in[4];
    const float* W1  = (const float*)d_in[5];
    const float* b1  = (const float*)d_in[6];
    const float* W2  = (const float*)d_in[7];
    const float* b2  = (const float*)d_in[8];
    const float* Wp1 = (const float*)d_in[9];
    const float* bp1 = (const float*)d_in[10];
    const float* Wp2 = (const float*)d_in[11];
    const float* bp2 = (const float*)d_in[12];
    const float* Wm  = (const float*)d_in[13];
    const float* bm  = (const float*)d_in[14];
    const float* gam = (const float*)d_in[15];
    const float* bet = (const float*)d_in[16];

    float* ws    = (float*)d_ws;
    float* stats = ws + OFF_STATS;
    f16*   esWT  = (f16*)(ws + OFF_ESWT);
    f16*   eh16  = (f16*)(ws + OFF_EH);
    int*   hist  = (int*)(ws + OFF_HIST);
    int*   rowp  = (int*)(ws + OFF_ROWPTR);
    int*   curs  = (int*)(ws + OFF_CURSOR);
    int*   cidx  = (int*)(ws + OFF_COLIDX);
    float* h1    = ws + OFF_H1;
    float* e_pre = ws + OFF_EPRE;
    float* out   = (float*)d_out;

    // one memset covers stats + esWT + eh16 + hist (contiguous)
    hipMemsetAsync(ws, 0, ZERO_FLOATS * sizeof(float), stream);

    hist_kernel<<<391, 256, 0, stream>>>(eSH, hist);
    scan_kernel<<<1, 1024, 0, stream>>>(hist, rowp, curs);
    scatter_kernel<<<391, 256, 0, stream>>>(eSH, curs, cidx);
    gcn_gather1<<<NSH, 256, 0, stream>>>(rowp, cidx, shemb, W1, b1, h1);
    gcn2_fused<<<NSH, 256, 0, stream>>>(rowp, cidx, h1, W2, b2,
                                        Wp1, bp1, Wp2, bp2, Wm, eh16, esWT);
    synd_mfma<<<512, 256, 0, stream>>>(presc, esWT, bm, e_pre, stats);
    out_fused<<<dim3(2, 1024), 256, 0, stream>>>(e_pre, eh16, stats, gam, bet, out);
}

// Round 6
// 230.699 us; speedup vs baseline: 1.8590x; 1.0012x over previous
//
#include <hip/hip_runtime.h>
#include <math.h>

#define NSH 1195
#define NU  805
#define NI  390
#define DD  64
#define BROWS 65536
#define ESH 100000
#define KPAD 416   // 13*32
#define NUPAD 832  // 13*64, eh16 padded rows

typedef _Float16 f16;
typedef _Float16 f16x2 __attribute__((ext_vector_type(2)));
typedef _Float16 f16x8 __attribute__((ext_vector_type(8)));
typedef float f32x4 __attribute__((ext_vector_type(4)));

// ---------------- ws layout (float units) ----------------
#define OFF_STATS  0u        // 128
#define OFF_ESWT   128u      // 64*416 f16 = 13312 floats
#define OFF_EH     13440u    // 832*64 f16 = 26624 floats
#define OFF_HIST   40064u    // 1280 ints
#define ZERO_FLOATS 41344u
#define OFF_ROWPTR 41344u    // 1280 ints
#define OFF_CURSOR 42624u    // 1280 ints
#define OFF_COLIDX 43904u    // 100096 ints
#define OFF_H1     144000u   // 76480
#define OFF_EPRE   220480u   // 4194304

// ---------------- CSR build ----------------
__global__ __launch_bounds__(256) void hist_kernel(const int* __restrict__ edges,
                                                   int* __restrict__ hist) {
    int e = blockIdx.x * 256 + threadIdx.x;
    if (e < ESH) atomicAdd(&hist[edges[ESH + e]], 1);
}

__global__ __launch_bounds__(1024) void scan_kernel(const int* __restrict__ hist,
                                                    int* __restrict__ row_ptr,
                                                    int* __restrict__ cursor) {
    __shared__ int s[2048];
    int t = threadIdx.x;
    s[t] = (t < NSH) ? hist[t] : 0;
    s[t + 1024] = (t + 1024 < NSH) ? hist[t + 1024] : 0;
    __syncthreads();
    for (int off = 1; off < 2048; off <<= 1) {
        int a = s[t], b = s[t + 1024];
        int aa = (t >= off) ? s[t - off] : 0;
        int bb = s[t + 1024 - off];
        __syncthreads();
        s[t] = a + aa;
        s[t + 1024] = b + bb;
        __syncthreads();
    }
    if (t == 0) row_ptr[0] = 0;
    for (int i = t; i < NSH; i += 1024) {
        row_ptr[i + 1] = s[i];
        cursor[i] = (i == 0) ? 0 : s[i - 1];
    }
}

__global__ __launch_bounds__(256) void scatter_kernel(const int* __restrict__ edges,
                                                      int* __restrict__ cursor,
                                                      int* __restrict__ col_idx) {
    int e = blockIdx.x * 256 + threadIdx.x;
    if (e < ESH) {
        int t = edges[ESH + e];
        int pos = atomicAdd(&cursor[t], 1);
        col_idx[pos] = edges[e];
    }
}

// ---------------- layer 1: gather + transform ----------------
__global__ __launch_bounds__(256) void gcn_gather1(const int* __restrict__ row_ptr,
                                                   const int* __restrict__ col_idx,
                                                   const float* __restrict__ x,
                                                   const float* __restrict__ W,
                                                   const float* __restrict__ b,
                                                   float* __restrict__ out) {
    __shared__ float s_wt[DD * DD];
    __shared__ float s_p[4 * DD];
    int tid = threadIdx.x;
    int w = tid >> 6, lane = tid & 63;
    for (int i = tid; i < DD * DD; i += 256) {
        int j = i >> 6, k = i & 63;
        s_wt[k * DD + j] = W[i];
    }
    int node = blockIdx.x;
    int beg = row_ptr[node], end = row_ptr[node + 1];
    float acc = 0.f;
    for (int e = beg + w; e < end; e += 4)
        acc += x[col_idx[e] * DD + lane];
    s_p[w * DD + lane] = acc;
    __syncthreads();
    float z = s_p[lane] + s_p[DD + lane] + s_p[2 * DD + lane] + s_p[3 * DD + lane];
    __syncthreads();
    if (w == 0) s_p[lane] = z;
    __syncthreads();
    float cntf = (float)(end - beg);
    float o = cntf * b[lane];
    #pragma unroll 8
    for (int k = 0; k < DD; k++)
        o = fmaf(s_p[k], s_wt[k * DD + lane], o);
    float h = tanhf(o / fmaxf(cntf, 1.f));
    if (w == 0) out[node * DD + lane] = h;
}

// ---------------- layer 2 fused ----------------
__global__ __launch_bounds__(256) void gcn2_fused(const int* __restrict__ row_ptr,
                                                  const int* __restrict__ col_idx,
                                                  const float* __restrict__ h1,
                                                  const float* __restrict__ W2,
                                                  const float* __restrict__ b2,
                                                  const float* __restrict__ Wp1,
                                                  const float* __restrict__ bp1,
                                                  const float* __restrict__ Wp2,
                                                  const float* __restrict__ bp2,
                                                  const float* __restrict__ Wm,
                                                  f16* __restrict__ eh16,
                                                  f16* __restrict__ esWT) {
    __shared__ float s_w2[DD * DD], s_p1[DD * DD], s_p2[DD * DD], s_wm[DD * DD];
    __shared__ float s_v[4 * DD];
    int tid = threadIdx.x;
    int w = tid >> 6, lane = tid & 63;
    for (int i = tid; i < DD * DD; i += 256) {
        int j = i >> 6, k = i & 63;
        s_w2[k * DD + j] = W2[i];
        s_p1[k * DD + j] = Wp1[i];
        s_p2[k * DD + j] = Wp2[i];
        s_wm[k * DD + j] = Wm[i];
    }
    int node = blockIdx.x;
    int beg = row_ptr[node], end = row_ptr[node + 1];
    float acc = 0.f;
    for (int e = beg + w; e < end; e += 4)
        acc += h1[col_idx[e] * DD + lane];
    s_v[w * DD + lane] = acc;
    __syncthreads();
    float z = s_v[lane] + s_v[DD + lane] + s_v[2 * DD + lane] + s_v[3 * DD + lane];
    __syncthreads();
    if (w == 0) s_v[lane] = z;
    __syncthreads();
    float cntf = (float)(end - beg);
    float o = cntf * b2[lane];
    #pragma unroll 8
    for (int k = 0; k < DD; k++)
        o = fmaf(s_v[k], s_w2[k * DD + lane], o);
    float h2v = tanhf(o / fmaxf(cntf, 1.f));
    __syncthreads();
    if (w == 0) s_v[lane] = h2v;
    __syncthreads();
    float t = bp1[lane];
    #pragma unroll 8
    for (int k = 0; k < DD; k++)
        t = fmaf(s_v[k], s_p1[k * DD + lane], t);
    t = t > 0.f ? t : expm1f(t);
    __syncthreads();
    if (w == 0) s_v[lane] = t;
    __syncthreads();
    float o2 = bp2[lane];
    #pragma unroll 8
    for (int k = 0; k < DD; k++)
        o2 = fmaf(s_v[k], s_p2[k * DD + lane], o2);
    float sq = o2 * o2;
    #pragma unroll
    for (int off = 1; off < 64; off <<= 1) sq += __shfl_xor(sq, off);
    float r = o2 / sqrtf(sq);
    if (node < NU) {
        if (w == 0) eh16[node * DD + lane] = (f16)r;
    } else {
        __syncthreads();
        if (w == 0) s_v[lane] = r;
        __syncthreads();
        float m = 0.f;
        #pragma unroll 8
        for (int k = 0; k < DD; k++)
            m = fmaf(s_v[k], s_wm[k * DD + lane], m);
        if (w == 0) esWT[lane * KPAD + (node - NU)] = (f16)m;
    }
}

// ---------------- synd_v2: LDS-staged P (f16), rowsum via ones-MFMA ----------------
// 1024 blocks x 64 rows. LDS s_P[64][416] f16 (zero-padded K). Coalesced float4
// stage; A-frags from LDS at b128 bandwidth floor; 5th B-tile = ones -> rowsum
// lands in C-layout (no shuffles).
__global__ __launch_bounds__(256) void synd_v2(const float* __restrict__ P,
                                               const f16* __restrict__ esWT,
                                               const float* __restrict__ bm,
                                               float* __restrict__ e_pre,
                                               float* __restrict__ stats) {
    __shared__ __align__(16) f16 s_P[64 * KPAD];   // 53248 B
    __shared__ float s_stats[128];
    int tid = threadIdx.x;
    if (tid < 128) s_stats[tid] = 0.f;

    // zero K-pad cols 390..415 (13 u32 per row)
    for (int i = tid; i < 64 * 13; i += 256) {
        int row = i / 13, j = i - row * 13;
        *(uint32_t*)&s_P[row * KPAD + 390 + j * 2] = 0u;
    }
    // stage: flat coalesced float4 over 64x390
    const float* Pb = P + (size_t)blockIdx.x * 64 * NI;
    for (int it = 0; it < 25; it++) {
        int f = it * 1024 + tid * 4;
        if (f < 64 * NI) {
            f32x4 v = *(const f32x4*)(Pb + f);
            int row = f / NI;               // compiler magic-div
            int col = f - row * NI;         // even, <= 388
            *(f16x2*)&s_P[row * KPAD + col] = (f16x2){(f16)v.x, (f16)v.y};
            int row2 = row, col2 = col + 2;
            if (col2 == NI) { row2 = row + 1; col2 = 0; }
            *(f16x2*)&s_P[row2 * KPAD + col2] = (f16x2){(f16)v.z, (f16)v.w};
        }
    }
    __syncthreads();

    int lane = tid & 63, w = tid >> 6;
    int l15 = lane & 15, lk = lane >> 4;
    int rowbase = blockIdx.x * 64 + w * 16;

    f32x4 acc[5];
    #pragma unroll
    for (int ni = 0; ni < 5; ni++) acc[ni] = (f32x4){0.f, 0.f, 0.f, 0.f};

    f16x8 ones;
    #pragma unroll
    for (int i = 0; i < 8; i++) ones[i] = (f16)1.0f;

    const f16* arow = &s_P[(w * 16 + l15) * KPAD];
    const f16* bp[4];
    #pragma unroll
    for (int ni = 0; ni < 4; ni++)
        bp[ni] = esWT + (size_t)(ni * 16 + l15) * KPAD;

    for (int step = 0; step < 13; step++) {
        int kb = step * 32 + lk * 8;
        f16x8 a = *(const f16x8*)(arow + kb);
        f16x8 bfr[4];
        #pragma unroll
        for (int ni = 0; ni < 4; ni++)
            bfr[ni] = *(const f16x8*)(bp[ni] + kb);
        #pragma unroll
        for (int ni = 0; ni < 4; ni++)
            acc[ni] = __builtin_amdgcn_mfma_f32_16x16x32_f16(a, bfr[ni], acc[ni], 0, 0, 0);
        acc[4] = __builtin_amdgcn_mfma_f32_16x16x32_f16(a, ones, acc[4], 0, 0, 0);
    }

    float bmv[4];
    #pragma unroll
    for (int ni = 0; ni < 4; ni++) bmv[ni] = bm[ni * 16 + l15];

    #pragma unroll
    for (int ni = 0; ni < 4; ni++) {
        float s = 0.f, q = 0.f;
        #pragma unroll
        for (int j = 0; j < 4; j++) {
            float v = acc[ni][j] / acc[4][j] + bmv[ni];
            int row = rowbase + lk * 4 + j;
            e_pre[(size_t)row * DD + ni * 16 + l15] = v;
            s += v;
            q = fmaf(v, v, q);
        }
        s += __shfl_xor(s, 16); s += __shfl_xor(s, 32);
        q += __shfl_xor(q, 16); q += __shfl_xor(q, 32);
        if (lk == 0) {
            atomicAdd(&s_stats[ni * 16 + l15], s);
            atomicAdd(&s_stats[64 + ni * 16 + l15], q);
        }
    }
    __syncthreads();
    if (tid < 128) atomicAdd(&stats[tid], s_stats[tid]);
}

// ---------------- out_v2: 4 col-groups (4/3/3/3 tiles), LDS 33KB, streamed stores ----------------
__global__ __launch_bounds__(256) void out_fused(const float* __restrict__ e_pre,
                                                 const f16* __restrict__ eh16,
                                                 const float* __restrict__ stats,
                                                 const float* __restrict__ gamma,
                                                 const float* __restrict__ beta,
                                                 float* __restrict__ out) {
    __shared__ __align__(16) f16 s_eh[256 * DD];   // <=32768 B
    __shared__ float s_bn[128];
    int tid = threadIdx.x;
    int cg = blockIdx.x;
    int t0 = (cg == 0) ? 0 : cg * 3 + 1;
    int nt = (cg == 0) ? 4 : 3;
    int cbase = t0 * 64;
    int nrows = nt * 64;

    if (tid < 64) {
        float mu  = stats[tid] * (1.0f / 65536.0f);
        float ex2 = stats[64 + tid] * (1.0f / 65536.0f);
        float var = ex2 - mu * mu;
        float rstd = 1.0f / sqrtf(var + 1e-5f);
        float sc = rstd * gamma[tid];
        s_bn[tid] = sc;
        s_bn[64 + tid] = beta[tid] - mu * sc;
    }

    const uint4* src = (const uint4*)(eh16 + (size_t)cbase * DD);
    int nchunks = nrows * 8;
    for (int c = tid; c < nchunks; c += 256) {
        int row = c >> 3, slot = c & 7;
        uint4 v = src[c];
        *(uint4*)&s_eh[row * DD + ((slot ^ (row & 7)) << 3)] = v;
    }
    __syncthreads();

    int lane = tid & 63, w = tid >> 6;
    int l15 = lane & 15, lk = lane >> 4;
    int r0 = blockIdx.y * 64 + w * 16;

    f16x8 afr[2];
    {
        const float* pr = e_pre + (size_t)(r0 + l15) * DD;
        #pragma unroll
        for (int ks = 0; ks < 2; ks++) {
            int kb = ks * 32 + lk * 8;
            f32x4 v0 = *(const f32x4*)&pr[kb];
            f32x4 v1 = *(const f32x4*)&pr[kb + 4];
            f16x8 a;
            #pragma unroll
            for (int i = 0; i < 4; i++) {
                a[i]     = (f16)fmaxf(fmaf(v0[i], s_bn[kb + i],     s_bn[64 + kb + i]),     0.f);
                a[4 + i] = (f16)fmaxf(fmaf(v1[i], s_bn[kb + 4 + i], s_bn[64 + kb + 4 + i]), 0.f);
            }
            afr[ks] = a;
        }
    }

    for (int tt = 0; tt < nt; tt++) {
        f32x4 acc[4];
        #pragma unroll
        for (int c16 = 0; c16 < 4; c16++) acc[c16] = (f32x4){0.f, 0.f, 0.f, 0.f};
        #pragma unroll
        for (int c16 = 0; c16 < 4; c16++) {
            int lc = tt * 64 + c16 * 16 + l15;
            #pragma unroll
            for (int ks = 0; ks < 2; ks++) {
                int slot = (ks * 4 + lk) ^ (lc & 7);
                f16x8 b = *(const f16x8*)&s_eh[lc * DD + (slot << 3)];
                acc[c16] = __builtin_amdgcn_mfma_f32_16x16x32_f16(afr[ks], b, acc[c16], 0, 0, 0);
            }
        }
        #pragma unroll
        for (int c16 = 0; c16 < 4; c16++) {
            int col = cbase + tt * 64 + c16 * 16 + l15;
            if (col < NU) {
                #pragma unroll
                for (int j = 0; j < 4; j++) {
                    int row = r0 + lk * 4 + j;
                    out[(size_t)row * NU + col] = acc[c16][j];
                }
            }
        }
    }
}

// ---------------- launcher ----------------
extern "C" void kernel_launch(void* const* d_in, const int* in_sizes, int n_in,
                              void* d_out, int out_size, void* d_ws, size_t ws_size,
                              hipStream_t stream) {
    const int*   eSH   = (const int*)d_in[0];
    const float* presc = (const float*)d_in[3];
    const float* shemb = (const float*)d_in[4];
    const float* W1  = (const float*)d_in[5];
    const float* b1  = (const float*)d_in[6];
    const float* W2  = (const float*)d_in[7];
    const float* b2  = (const float*)d_in[8];
    const float* Wp1 = (const float*)d_in[9];
    const float* bp1 = (const float*)d_in[10];
    const float* Wp2 = (const float*)d_in[11];
    const float* bp2 = (const float*)d_in[12];
    const float* Wm  = (const float*)d_in[13];
    const float* bm  = (const float*)d_in[14];
    const float* gam = (const float*)d_in[15];
    const float* bet = (const float*)d_in[16];

    float* ws    = (float*)d_ws;
    float* stats = ws + OFF_STATS;
    f16*   esWT  = (f16*)(ws + OFF_ESWT);
    f16*   eh16  = (f16*)(ws + OFF_EH);
    int*   hist  = (int*)(ws + OFF_HIST);
    int*   rowp  = (int*)(ws + OFF_ROWPTR);
    int*   curs  = (int*)(ws + OFF_CURSOR);
    int*   cidx  = (int*)(ws + OFF_COLIDX);
    float* h1    = ws + OFF_H1;
    float* e_pre = ws + OFF_EPRE;
    float* out   = (float*)d_out;

    hipMemsetAsync(ws, 0, ZERO_FLOATS * sizeof(float), stream);

    hist_kernel<<<391, 256, 0, stream>>>(eSH, hist);
    scan_kernel<<<1, 1024, 0, stream>>>(hist, rowp, curs);
    scatter_kernel<<<391, 256, 0, stream>>>(eSH, curs, cidx);
    gcn_gather1<<<NSH, 256, 0, stream>>>(rowp, cidx, shemb, W1, b1, h1);
    gcn2_fused<<<NSH, 256, 0, stream>>>(rowp, cidx, h1, W2, b2,
                                        Wp1, bp1, Wp2, bp2, Wm, eh16, esWT);
    synd_v2<<<1024, 256, 0, stream>>>(presc, esWT, bm, e_pre, stats);
    out_fused<<<dim3(4, 1024), 256, 0, stream>>>(e_pre, eh16, stats, gam, bet, out);
}